// Round 6
// baseline (831.792 us; speedup 1.0000x reference)
//
#include <hip/hip_runtime.h>

#define N_NODES   50000
#define N_EDGES   1600000
#define N_GRAPHS  512
#define LAYERS    3
#define D         128
#define EF        16
#define BN_EPS    1e-5f

#define SCAN_CH   256
#define SCAN_NB   ((N_NODES + SCAN_CH - 1) / SCAN_CH)   // 196

#define NCHUNK    (N_EDGES / 16)        // 100000 (E % 16 == 0)
#define AGGR_BLK  1024
#define AGGR_WPB  4
#define NWAVES    (AGGR_BLK * AGGR_WPB) // 4096
#define ELDS_STR  130                   // dwords: 2-way (free) write banks

#define SCAT_ILP  4
#define SCAT_TILE (256 * SCAT_ILP)      // 1024 edges per block
#define SCAT_NB   ((N_EDGES + SCAT_TILE - 1) / SCAT_TILE)  // 1563

typedef unsigned int u32;
typedef short bf16x8 __attribute__((ext_vector_type(8)));
typedef float f32x4 __attribute__((ext_vector_type(4)));

__device__ __forceinline__ unsigned short f2bf(float f) {   // RNE f32->bf16
    unsigned u = __builtin_bit_cast(unsigned, f);
    u += 0x7FFF + ((u >> 16) & 1);
    return (unsigned short)(u >> 16);
}

__device__ __forceinline__ float bf2f(unsigned short u) {
    return __builtin_bit_cast(float, (unsigned)u << 16);
}

__device__ __forceinline__ float lo16f(u32 u) {
    return __builtin_bit_cast(float, u << 16);
}
__device__ __forceinline__ float hi16f(u32 u) {
    return __builtin_bit_cast(float, u & 0xFFFF0000u);
}

__device__ __forceinline__ u32 pack_bf2(float x, float y) {
    return ((u32)f2bf(x)) | ((u32)f2bf(y) << 16);
}

// ---------------------------------------------------------------------------
// CSR build step 1: histogram of dst (counts pre-zeroed).
// ---------------------------------------------------------------------------
__global__ __launch_bounds__(256) void hist_kernel(
    const int* __restrict__ dst, int* __restrict__ counts)
{
    int e = blockIdx.x * 256 + threadIdx.x;
    atomicAdd(&counts[dst[e]], 1);
}

// ---------------------------------------------------------------------------
// Hierarchical scan, 3 phases.
// ---------------------------------------------------------------------------
__global__ __launch_bounds__(256) void scan1_kernel(
    const int* __restrict__ counts, int* __restrict__ blocksum)
{
    const int t = threadIdx.x;
    const int i = blockIdx.x * SCAN_CH + t;
    int v = (i < N_NODES) ? counts[i] : 0;
    #pragma unroll
    for (int off = 32; off > 0; off >>= 1)
        v += __shfl_down(v, off);
    __shared__ int ws[4];
    if ((t & 63) == 0) ws[t >> 6] = v;
    __syncthreads();
    if (t == 0) blocksum[blockIdx.x] = ws[0] + ws[1] + ws[2] + ws[3];
}

__global__ __launch_bounds__(256) void scan2_kernel(
    const int* __restrict__ blocksum, int* __restrict__ blockbase)
{
    __shared__ int s[256];
    const int t = threadIdx.x;
    int v = (t < SCAN_NB) ? blocksum[t] : 0;
    s[t] = v;
    __syncthreads();
    for (int off = 1; off < 256; off <<= 1) {
        int u = (t >= off) ? s[t - off] : 0;
        __syncthreads();
        s[t] += u;
        __syncthreads();
    }
    if (t < SCAN_NB) blockbase[t] = s[t] - v;
}

__global__ __launch_bounds__(256) void scan3_kernel(
    const int* __restrict__ counts, const int* __restrict__ blockbase,
    int* __restrict__ offsets, int* __restrict__ cursor)
{
    __shared__ int s[256];
    const int t = threadIdx.x;
    const int i = blockIdx.x * SCAN_CH + t;
    int v = (i < N_NODES) ? counts[i] : 0;
    s[t] = v;
    __syncthreads();
    for (int off = 1; off < 256; off <<= 1) {
        int u = (t >= off) ? s[t - off] : 0;
        __syncthreads();
        s[t] += u;
        __syncthreads();
    }
    if (i < N_NODES) {
        const int base = blockbase[blockIdx.x];
        const int excl = base + s[t] - v;
        offsets[i] = excl;
        cursor[i]  = excl;
        if (i == N_NODES - 1) offsets[N_NODES] = base + s[t];
    }
}

// ---------------------------------------------------------------------------
// Scatter v2 (ILP-4): edges into dst-sorted order; edge_attr -> bf16
// (32B/edge) + packed {src,dst} int2 (one 8B store).  4 independent
// atomic->store chains per thread hide the cross-XCD atomic latency.
// ---------------------------------------------------------------------------
__global__ __launch_bounds__(256) void scatter_kernel(
    const int* __restrict__ src, const int* __restrict__ dst,
    const float* __restrict__ edge_attr,
    int* __restrict__ cursor, int2* __restrict__ srcdst,
    uint4* __restrict__ sorted_eah)
{
    const int e0 = blockIdx.x * SCAT_TILE + threadIdx.x;

    int e[SCAT_ILP], d[SCAT_ILP], s[SCAT_ILP], pos[SCAT_ILP];
    bool ok[SCAT_ILP];
    #pragma unroll
    for (int i = 0; i < SCAT_ILP; ++i) {
        e[i]  = e0 + i * 256;
        ok[i] = e[i] < N_EDGES;
        int ec = ok[i] ? e[i] : 0;
        d[i] = dst[ec];
        s[i] = src[ec];
    }
    #pragma unroll
    for (int i = 0; i < SCAT_ILP; ++i)
        if (ok[i]) pos[i] = atomicAdd(&cursor[d[i]], 1);

    #pragma unroll
    for (int i = 0; i < SCAT_ILP; ++i) {
        if (!ok[i]) continue;
        const float4* ea = (const float4*)(edge_attr + (size_t)e[i] * EF);
        float4 a0 = ea[0], a1 = ea[1], a2 = ea[2], a3 = ea[3];
        uint4 o0, o1;
        o0.x = pack_bf2(a0.x, a0.y); o0.y = pack_bf2(a0.z, a0.w);
        o0.z = pack_bf2(a1.x, a1.y); o0.w = pack_bf2(a1.z, a1.w);
        o1.x = pack_bf2(a2.x, a2.y); o1.y = pack_bf2(a2.z, a2.w);
        o1.z = pack_bf2(a3.x, a3.y); o1.w = pack_bf2(a3.z, a3.w);
        sorted_eah[(size_t)pos[i] * 2]     = o0;
        sorted_eah[(size_t)pos[i] * 2 + 1] = o1;
        srcdst[pos[i]] = make_int2(s[i], d[i]);
    }
}

// ---------------------------------------------------------------------------
// Graph offsets: batch is sorted; goff[g] = lower_bound(batch, g), goff[512]=N.
// ---------------------------------------------------------------------------
__global__ __launch_bounds__(512) void goff_kernel(
    const int* __restrict__ batch, int* __restrict__ goff)
{
    const int g = threadIdx.x;
    int lo = 0, hi = N_NODES;
    while (lo < hi) {
        int mid = (lo + hi) >> 1;
        if (batch[mid] < g) lo = mid + 1; else hi = mid;
    }
    goff[g] = lo;
    if (g == 0) goff[N_GRAPHS] = N_NODES;
}

// ---------------------------------------------------------------------------
// Weight prep: transpose W1/W2 (all layers) to bf16 Wt[out][k], once per call.
// ---------------------------------------------------------------------------
__global__ __launch_bounds__(256) void wprep_kernel(
    const float* __restrict__ W1, const float* __restrict__ W2,
    unsigned short* __restrict__ Wt)
{
    const int matid = blockIdx.x;          // l*2 + (0:W1, 1:W2)
    const int l = matid >> 1;
    const float* srcm = (matid & 1) ? (W2 + (size_t)l * D * D)
                                    : (W1 + (size_t)l * D * D);
    unsigned short* out = Wt + (size_t)matid * D * D;
    for (int i = 0; i < 64; ++i) {
        int idx = threadIdx.x + i * 256;
        int k = idx >> 7, n = idx & 127;
        out[n * D + k] = f2bf(srcm[idx]);
    }
}

// ---------------------------------------------------------------------------
// elW B-fragment prep (verified): per layer, 8 tiles x 64 lanes x 8 bf16.
// k 0..15 = elW; k16 = elb (bias trick); k17..31 = 0.
// ---------------------------------------------------------------------------
__global__ __launch_bounds__(512) void elprep_kernel(
    const float* __restrict__ elW, const float* __restrict__ elb,
    uint4* __restrict__ elWf)                 // [LAYERS][8][64]
{
    const int l    = blockIdx.x;
    const int t    = threadIdx.x >> 6;
    const int lane = threadIdx.x & 63;
    const int q = lane >> 4, c = lane & 15;
    const float* W = elW + (size_t)l * EF * D;
    unsigned short h[8];
    #pragma unroll
    for (int i = 0; i < 8; ++i) {
        int k = q * 8 + i;
        float v = 0.f;
        if (q < 2)                 v = W[k * D + t * 16 + c];
        else if (q == 2 && i == 0) v = elb[l * D + t * 16 + c];
        h[i] = f2bf(v);
    }
    uint4 o;
    o.x = (u32)h[0] | ((u32)h[1] << 16);
    o.y = (u32)h[2] | ((u32)h[3] << 16);
    o.z = (u32)h[4] | ((u32)h[5] << 16);
    o.w = (u32)h[6] | ((u32)h[7] << 16);
    elWf[((size_t)l * 8 + t) * 64 + lane] = o;
}

// ---------------------------------------------------------------------------
// x -> bf16 (once per call).
// ---------------------------------------------------------------------------
__global__ __launch_bounds__(256) void xprep_kernel(
    const float* __restrict__ x, unsigned short* __restrict__ xb)
{
    int i = blockIdx.x * 256 + threadIdx.x;
    xb[i] = f2bf(x[i]);
}

// ---------------------------------------------------------------------------
// Per-layer aggregation v6 (edge-tiled MFMA, latency-batched phase 2):
//   zin_f[n][:] += sum_{e: dst=n} relu(h[src_e] + ea_e@elW + elb)  (fp32 atomics)
// 4096 waves x contiguous dst-sorted 16-edge chunks. Per chunk:
//   - s_load 16 packed {src,dst} pairs (wave-uniform)
//   - issue 32 coalesced ushort h-gathers (lane owns feats l, l+64)
//   - MFMA E = ea@elW+elb -> per-wave LDS slice (no barriers)
//   - 32 ds_read_b32, conflict-free (lane-linear)
//   - register-only serial segmented accumulate; flush = 2 atomics on
//     dst-change (uniform branch).  (+h[n] self term folded into node_mlp.)
// ---------------------------------------------------------------------------
__global__ __launch_bounds__(256) void aggr_kernel(
    const unsigned short* __restrict__ h_b,    // [N][128] bf16
    const uint4* __restrict__ sorted_ea,       // [E] 2 x uint4 (bf16x16)
    const int*   __restrict__ srcdst,          // [E] packed {src,dst}, dst nondecr.
    const uint4* __restrict__ elWf,            // [8][64] this layer
    float* __restrict__ zin_f)                 // [N][128] f32, pre-zeroed
{
    __shared__ float e_lds_all[AGGR_WPB][16 * ELDS_STR];
    const int tid  = threadIdx.x;
    const int wv   = __builtin_amdgcn_readfirstlane(tid >> 6);
    const int lane = tid & 63;
    const int q    = lane >> 4;
    const int c    = lane & 15;
    const int w    = blockIdx.x * AGGR_WPB + wv;

    float* e_lds = e_lds_all[wv];

    // B fragments (verified layout), L2-resident
    bf16x8 bfr[8];
    #pragma unroll
    for (int t = 0; t < 8; ++t)
        bfr[t] = __builtin_bit_cast(bf16x8, elWf[t * 64 + lane]);

    // A-frag masks: q<2 pass ea; q2 -> k16 = bf16(1.0) bias row; q3 -> 0
    const u32 mand = (q < 2) ? 0xFFFFFFFFu : 0u;
    const u32 mor0 = (q == 2) ? 0x3F80u : 0u;

    const int qc = NCHUNK / NWAVES, rc = NCHUNK % NWAVES;
    const int c0 = w * qc + (w < rc ? w : rc);
    const int cn = qc + (w < rc ? 1 : 0);
    const int e_lo = c0 * 16;
    const int e_hi = (c0 + cn) * 16;

    int cur = srcdst[(size_t)e_lo * 2 + 1];   // first dst, wave-uniform
    float accA = 0.f, accB = 0.f;
    const f32x4 zero4 = (f32x4){0.f, 0.f, 0.f, 0.f};

#define HLOAD(I, SV)                                                          \
    const u32 hA##I = h_b[(size_t)(SV) * D + lane];                           \
    const u32 hB##I = h_b[(size_t)(SV) * D + 64 + lane];

#define EREAD(I)                                                              \
    const float eA##I = e_lds[(I) * ELDS_STR + lane];                         \
    const float eB##I = e_lds[(I) * ELDS_STR + 64 + lane];

#define ACC(I, DV)                                                            \
    {                                                                         \
        if ((DV) != cur) {                                                    \
            atomicAdd(&zin_f[(size_t)cur * D + lane],      accA);             \
            atomicAdd(&zin_f[(size_t)cur * D + 64 + lane], accB);             \
            accA = 0.f; accB = 0.f; cur = (DV);                               \
        }                                                                     \
        accA += fmaxf(eA##I + bf2f((unsigned short)hA##I), 0.f);              \
        accB += fmaxf(eB##I + bf2f((unsigned short)hB##I), 0.f);              \
    }

    for (int e0 = e_lo; e0 < e_hi; e0 += 16) {
        // --- wave-uniform packed ids: 8 x int4 = (s,d,s,d) ---
        const int4* sp = (const int4*)(srcdst + (size_t)e0 * 2);
        const int4 p0 = sp[0], p1 = sp[1], p2 = sp[2], p3 = sp[3];
        const int4 p4 = sp[4], p5 = sp[5], p6 = sp[6], p7 = sp[7];

        // --- issue all 32 coalesced h gathers (latency hides under MFMA) ---
        HLOAD(0,  p0.x) HLOAD(1,  p0.z) HLOAD(2,  p1.x) HLOAD(3,  p1.z)
        HLOAD(4,  p2.x) HLOAD(5,  p2.z) HLOAD(6,  p3.x) HLOAD(7,  p3.z)
        HLOAD(8,  p4.x) HLOAD(9,  p4.z) HLOAD(10, p5.x) HLOAD(11, p5.z)
        HLOAD(12, p6.x) HLOAD(13, p6.z) HLOAD(14, p7.x) HLOAD(15, p7.z)

        // --- phase 1: E = ea@elW + elb -> LDS (f32) ---
        uint4 araw = sorted_ea[(size_t)(e0 + c) * 2 + (q & 1)];
        uint4 aw;
        aw.x = (araw.x & mand) | mor0;
        aw.y =  araw.y & mand;
        aw.z =  araw.z & mand;
        aw.w =  araw.w & mand;
        const bf16x8 afr = __builtin_bit_cast(bf16x8, aw);

        #pragma unroll
        for (int t = 0; t < 8; ++t) {
            f32x4 C = __builtin_amdgcn_mfma_f32_16x16x32_bf16(
                afr, bfr[t], zero4, 0, 0, 0);
            #pragma unroll
            for (int rr = 0; rr < 4; ++rr)
                e_lds[(q * 4 + rr) * ELDS_STR + t * 16 + c] = C[rr];
        }
        // same-wave LDS RAW: compiler inserts lgkmcnt waits

        // --- batch-read all 32 E values (conflict-free b32) ---
        EREAD(0)  EREAD(1)  EREAD(2)  EREAD(3)
        EREAD(4)  EREAD(5)  EREAD(6)  EREAD(7)
        EREAD(8)  EREAD(9)  EREAD(10) EREAD(11)
        EREAD(12) EREAD(13) EREAD(14) EREAD(15)

        // --- register-only serial segmented accumulate ---
        ACC(0,  p0.y) ACC(1,  p0.w) ACC(2,  p1.y) ACC(3,  p1.w)
        ACC(4,  p2.y) ACC(5,  p2.w) ACC(6,  p3.y) ACC(7,  p3.w)
        ACC(8,  p4.y) ACC(9,  p4.w) ACC(10, p5.y) ACC(11, p5.w)
        ACC(12, p6.y) ACC(13, p6.w) ACC(14, p7.y) ACC(15, p7.w)
    }
#undef HLOAD
#undef EREAD
#undef ACC

    atomicAdd(&zin_f[(size_t)cur * D + lane],      accA);
    atomicAdd(&zin_f[(size_t)cur * D + 64 + lane], accB);
}

// ---------------------------------------------------------------------------
// Fused node MLP via MFMA (bf16 in, fp32 accumulate):
//   hout_b = bf16(relu(relu(BN((h+zin_f)@W1+b1))@W2 + b2))
// The +h and f32->bf16 of the aggregation are folded into the A-frag load.
// In-place h update is safe: each block reads/writes only its own 64 rows.
// ---------------------------------------------------------------------------
__global__ __launch_bounds__(128) void node_mlp(
    const float* __restrict__ zin_f,            // [N][128] f32 (aggr sums)
    const unsigned short* __restrict__ h_in,    // [N][128] bf16 (layer input)
    const unsigned short* __restrict__ W1t,     // [128 out][128 k] bf16
    const float* __restrict__ b1,
    const float* __restrict__ bng, const float* __restrict__ bnb,
    const float* __restrict__ bnm, const float* __restrict__ bnv,
    const unsigned short* __restrict__ W2t,
    const float* __restrict__ b2,
    unsigned short* __restrict__ hout_b)
{
    __shared__ unsigned short zmid[64 * 136];   // 17.4 KB
    __shared__ float scale_s[128], shift_s[128], b2_s[128];

    const int tid  = threadIdx.x;
    const int wv   = tid >> 6;
    const int lane = tid & 63;
    const int q    = lane >> 4;
    const int m    = lane & 15;
    const int node0 = blockIdx.x * 64;

    {
        float sc = bng[tid] * rsqrtf(bnv[tid] + BN_EPS);
        scale_s[tid] = sc;
        shift_s[tid] = b1[tid] * sc + bnb[tid] - bnm[tid] * sc;
        b2_s[tid]    = b2[tid];
    }

    // A fragments: bf16(h + zin_f)
    bf16x8 a[2][4];
    #pragma unroll
    for (int sub = 0; sub < 2; ++sub) {
        int node = node0 + wv * 32 + sub * 16 + m;
        if (node >= N_NODES) node = N_NODES - 1;
        const float* zr = zin_f + (size_t)node * D;
        const unsigned short* hr = h_in + (size_t)node * D;
        #pragma unroll
        for (int kk = 0; kk < 4; ++kk) {
            const int base = kk * 32 + q * 8;
            float4 z0 = *(const float4*)(zr + base);
            float4 z1 = *(const float4*)(zr + base + 4);
            uint4  hv = *(const uint4*)(hr + base);
            bf16x8 t;
            t[0] = (short)f2bf(z0.x + lo16f(hv.x));
            t[1] = (short)f2bf(z0.y + hi16f(hv.x));
            t[2] = (short)f2bf(z0.z + lo16f(hv.y));
            t[3] = (short)f2bf(z0.w + hi16f(hv.y));
            t[4] = (short)f2bf(z1.x + lo16f(hv.z));
            t[5] = (short)f2bf(z1.y + hi16f(hv.z));
            t[6] = (short)f2bf(z1.z + lo16f(hv.w));
            t[7] = (short)f2bf(z1.w + hi16f(hv.w));
            a[sub][kk] = t;
        }
    }

    f32x4 acc[2][8];
    #pragma unroll
    for (int s2 = 0; s2 < 2; ++s2)
        #pragma unroll
        for (int t = 0; t < 8; ++t)
            acc[s2][t] = (f32x4){0.f, 0.f, 0.f, 0.f};

    __syncthreads();

    #pragma unroll
    for (int t = 0; t < 8; ++t) {
        const unsigned short* wrow = W1t + (size_t)(t * 16 + m) * D;
        bf16x8 bfr[4];
        #pragma unroll
        for (int k = 0; k < 4; ++k)
            bfr[k] = __builtin_bit_cast(bf16x8, *(const uint4*)&wrow[k * 32 + q * 8]);
        #pragma unroll
        for (int sub = 0; sub < 2; ++sub) {
            acc[sub][t] = __builtin_amdgcn_mfma_f32_16x16x32_bf16(a[sub][0], bfr[0], acc[sub][t], 0, 0, 0);
            acc[sub][t] = __builtin_amdgcn_mfma_f32_16x16x32_bf16(a[sub][1], bfr[1], acc[sub][t], 0, 0, 0);
            acc[sub][t] = __builtin_amdgcn_mfma_f32_16x16x32_bf16(a[sub][2], bfr[2], acc[sub][t], 0, 0, 0);
            acc[sub][t] = __builtin_amdgcn_mfma_f32_16x16x32_bf16(a[sub][3], bfr[3], acc[sub][t], 0, 0, 0);
        }
    }

    #pragma unroll
    for (int sub = 0; sub < 2; ++sub)
        #pragma unroll
        for (int t = 0; t < 8; ++t) {
            int col = t * 16 + m;
            float sc = scale_s[col], sh = shift_s[col];
            #pragma unroll
            for (int rr = 0; rr < 4; ++rr) {
                float v = fmaxf(acc[sub][t][rr] * sc + sh, 0.f);
                int row = wv * 32 + sub * 16 + q * 4 + rr;
                zmid[row * 136 + col] = f2bf(v);
            }
        }

    __syncthreads();

    bf16x8 a2[2][4];
    #pragma unroll
    for (int sub = 0; sub < 2; ++sub) {
        const unsigned short* zr = &zmid[(wv * 32 + sub * 16 + m) * 136];
        #pragma unroll
        for (int k = 0; k < 4; ++k)
            a2[sub][k] = __builtin_bit_cast(bf16x8, *(const uint4*)&zr[k * 32 + q * 8]);
    }

    #pragma unroll
    for (int s2 = 0; s2 < 2; ++s2)
        #pragma unroll
        for (int t = 0; t < 8; ++t)
            acc[s2][t] = (f32x4){0.f, 0.f, 0.f, 0.f};

    #pragma unroll
    for (int t = 0; t < 8; ++t) {
        const unsigned short* wrow = W2t + (size_t)(t * 16 + m) * D;
        bf16x8 bfr[4];
        #pragma unroll
        for (int k = 0; k < 4; ++k)
            bfr[k] = __builtin_bit_cast(bf16x8, *(const uint4*)&wrow[k * 32 + q * 8]);
        #pragma unroll
        for (int sub = 0; sub < 2; ++sub) {
            acc[sub][t] = __builtin_amdgcn_mfma_f32_16x16x32_bf16(a2[sub][0], bfr[0], acc[sub][t], 0, 0, 0);
            acc[sub][t] = __builtin_amdgcn_mfma_f32_16x16x32_bf16(a2[sub][1], bfr[1], acc[sub][t], 0, 0, 0);
            acc[sub][t] = __builtin_amdgcn_mfma_f32_16x16x32_bf16(a2[sub][2], bfr[2], acc[sub][t], 0, 0, 0);
            acc[sub][t] = __builtin_amdgcn_mfma_f32_16x16x32_bf16(a2[sub][3], bfr[3], acc[sub][t], 0, 0, 0);
        }
    }

    #pragma unroll
    for (int sub = 0; sub < 2; ++sub)
        #pragma unroll
        for (int rr = 0; rr < 4; ++rr) {
            int node = node0 + wv * 32 + sub * 16 + q * 4 + rr;
            if (node < N_NODES) {
                unsigned short* hrow = hout_b + (size_t)node * D;
                #pragma unroll
                for (int t = 0; t < 8; ++t) {
                    int col = t * 16 + m;
                    hrow[col] = f2bf(fmaxf(acc[sub][t][rr] + b2_s[col], 0.f));
                }
            }
        }
}

// ---------------------------------------------------------------------------
// Pool: segmented sum over sorted batch (bf16 in, fp32 out).
// ---------------------------------------------------------------------------
__global__ __launch_bounds__(512) void pool_kernel(
    const unsigned short* __restrict__ hout_b, const int* __restrict__ goff,
    float* __restrict__ pool, int layer_off)
{
    __shared__ float part[3][128];
    const int g = blockIdx.x;
    const int j = threadIdx.x & 127;
    const int grp = threadIdx.x >> 7;
    const int beg = goff[g], end = goff[g + 1];
    const int len = end - beg;
    const int ch  = (len + 3) >> 2;
    int lo = beg + grp * ch;
    int hi = lo + ch;
    if (hi > end) hi = end;
    float acc = 0.0f;
    for (int r = lo; r < hi; ++r)
        acc += bf2f(hout_b[(size_t)r * D + j]);
    if (grp) part[grp - 1][j] = acc;
    __syncthreads();
    if (grp == 0)
        pool[g * (LAYERS * D) + layer_off + j] =
            acc + part[0][j] + part[1][j] + part[2][j];
}

// ---------------------------------------------------------------------------
// Head: out[g] = relu(pool[g] @ lin1_W + lin1_b) @ lin2_W + lin2_b
// ---------------------------------------------------------------------------
__global__ __launch_bounds__(384) void head_kernel(
    const float* __restrict__ pool,
    const float* __restrict__ lin1W,
    const float* __restrict__ lin1b,
    const float* __restrict__ lin2W,
    const float* __restrict__ lin2b,
    float*       __restrict__ out)
{
    __shared__ float gs[LAYERS * D];
    __shared__ float red[LAYERS * D];
    const int g   = blockIdx.x;
    const int tid = threadIdx.x;
    gs[tid] = pool[g * (LAYERS * D) + tid];
    __syncthreads();

    float acc = lin1b[tid];
    #pragma unroll 4
    for (int k = 0; k < LAYERS * D; ++k)
        acc = fmaf(gs[k], lin1W[k * (LAYERS * D) + tid], acc);
    acc = fmaxf(acc, 0.0f);
    float p = acc * lin2W[tid];

    red[tid] = p;
    __syncthreads();
    if (tid < 128) red[tid] = red[tid] + red[tid + 128] + red[tid + 256];
    __syncthreads();
    if (tid < 64) {
        float v = red[tid] + red[tid + 64];
        v += __shfl_down(v, 32);
        v += __shfl_down(v, 16);
        v += __shfl_down(v, 8);
        v += __shfl_down(v, 4);
        v += __shfl_down(v, 2);
        v += __shfl_down(v, 1);
        if (tid == 0) out[g] = v + lin2b[0];
    }
}

// ---------------------------------------------------------------------------
extern "C" void kernel_launch(void* const* d_in, const int* in_sizes, int n_in,
                              void* d_out, int out_size, void* d_ws, size_t ws_size,
                              hipStream_t stream)
{
    const float* x         = (const float*)d_in[0];
    const float* edge_attr = (const float*)d_in[1];
    const float* elW       = (const float*)d_in[2];
    const float* elb       = (const float*)d_in[3];
    const float* W1        = (const float*)d_in[4];
    const float* b1        = (const float*)d_in[5];
    const float* bn_g      = (const float*)d_in[6];
    const float* bn_b      = (const float*)d_in[7];
    const float* bn_mean   = (const float*)d_in[8];
    const float* bn_var    = (const float*)d_in[9];
    const float* W2        = (const float*)d_in[10];
    const float* b2        = (const float*)d_in[11];
    const float* lin1W     = (const float*)d_in[12];
    const float* lin1b     = (const float*)d_in[13];
    const float* lin2W     = (const float*)d_in[14];
    const float* lin2b     = (const float*)d_in[15];
    const int*   ei        = (const int*)d_in[16];
    const int*   batch     = (const int*)d_in[17];
    const int*   src = ei;
    const int*   dst = ei + N_EDGES;

    // Workspace layout, all 16B-aligned:
    float*          pool       = (float*)d_ws;                              // G*384 f32
    unsigned short* xb         = (unsigned short*)(pool + (size_t)N_GRAPHS * LAYERS * D);
    unsigned short* hA_b       = xb   + (size_t)N_NODES * D;                // bf16
    float*          zin_f      = (float*)(hA_b + (size_t)N_NODES * D);      // [N][128] f32
    unsigned short* Wt         = (unsigned short*)(zin_f + (size_t)N_NODES * D);
    uint4*          elWf       = (uint4*)(Wt + 6 * D * D);                  // 3*8*64 uint4
    u32*            sorted_eah = (u32*)(elWf + LAYERS * 8 * 64);            // E*8 u32
    int*            srcdst     = (int*)(sorted_eah + (size_t)N_EDGES * 8);  // E int2
    int*            counts     = srcdst + (size_t)N_EDGES * 2;
    int*            offsets    = counts + N_NODES;                          // N+1
    int*            cursor     = offsets + N_NODES + 4;
    int*            goff       = cursor + N_NODES + 4;                      // 513 ints
    int*            blocksum   = goff + N_GRAPHS + 4;
    int*            blockbase  = blocksum + SCAN_NB + 4;

    hipMemsetAsync(counts, 0, (size_t)N_NODES * sizeof(int), stream);

    // --- once-per-call prep ---
    wprep_kernel<<<6, 256, 0, stream>>>(W1, W2, Wt);
    elprep_kernel<<<LAYERS, 512, 0, stream>>>(elW, elb, elWf);
    xprep_kernel<<<(N_NODES * D) / 256, 256, 0, stream>>>(x, xb);
    goff_kernel<<<1, 512, 0, stream>>>(batch, goff);
    hist_kernel<<<N_EDGES / 256, 256, 0, stream>>>(dst, counts);
    scan1_kernel<<<SCAN_NB, 256, 0, stream>>>(counts, blocksum);
    scan2_kernel<<<1, 256, 0, stream>>>(blocksum, blockbase);
    scan3_kernel<<<SCAN_NB, 256, 0, stream>>>(counts, blockbase, offsets, cursor);
    scatter_kernel<<<SCAT_NB, 256, 0, stream>>>(
        src, dst, edge_attr, cursor, (int2*)srcdst, (uint4*)sorted_eah);

    const unsigned short* hin_b = xb;
    for (int l = 0; l < LAYERS; ++l) {
        hipMemsetAsync(zin_f, 0, (size_t)N_NODES * D * sizeof(float), stream);
        aggr_kernel<<<AGGR_BLK, 256, 0, stream>>>(
            hin_b, (const uint4*)sorted_eah, srcdst,
            elWf + (size_t)l * 8 * 64, zin_f);
        node_mlp<<<(N_NODES + 63) / 64, 128, 0, stream>>>(
            zin_f, hin_b,
            Wt + (size_t)(l * 2)     * D * D, b1 + l * D,
            bn_g + l * D, bn_b + l * D, bn_mean + l * D, bn_var + l * D,
            Wt + (size_t)(l * 2 + 1) * D * D, b2 + l * D,
            hA_b);
        pool_kernel<<<N_GRAPHS, 512, 0, stream>>>(hA_b, goff, pool, l * D);
        hin_b = hA_b;
    }

    head_kernel<<<N_GRAPHS, LAYERS * D, 0, stream>>>(
        pool, lin1W, lin1b, lin2W, lin2b, (float*)d_out);
}

// Round 7
// 787.758 us; speedup vs baseline: 1.0559x; 1.0559x over previous
//
#include <hip/hip_runtime.h>

#define N_NODES   50000
#define N_EDGES   1600000
#define N_GRAPHS  512
#define LAYERS    3
#define D         128
#define EF        16
#define BN_EPS    1e-5f

#define SCAN_CH   256
#define SCAN_NB   ((N_NODES + SCAN_CH - 1) / SCAN_CH)   // 196

#define NCHUNK    (N_EDGES / 16)        // 100000 (E % 16 == 0)
#define AGGR_BLK  1024
#define AGGR_WPB  4
#define NWAVES    (AGGR_BLK * AGGR_WPB) // 4096
#define ELDS_STR  130                   // dwords: 2-way (free) write banks

typedef unsigned int u32;
typedef short bf16x8 __attribute__((ext_vector_type(8)));
typedef float f32x4 __attribute__((ext_vector_type(4)));

__device__ __forceinline__ unsigned short f2bf(float f) {   // RNE f32->bf16
    unsigned u = __builtin_bit_cast(unsigned, f);
    u += 0x7FFF + ((u >> 16) & 1);
    return (unsigned short)(u >> 16);
}

__device__ __forceinline__ float bf2f(unsigned short u) {
    return __builtin_bit_cast(float, (unsigned)u << 16);
}

__device__ __forceinline__ float lo16f(u32 u) {
    return __builtin_bit_cast(float, u << 16);
}
__device__ __forceinline__ float hi16f(u32 u) {
    return __builtin_bit_cast(float, u & 0xFFFF0000u);
}

__device__ __forceinline__ u32 pack_bf2(float x, float y) {
    return ((u32)f2bf(x)) | ((u32)f2bf(y) << 16);
}

// ---------------------------------------------------------------------------
// CSR build step 1: histogram of dst (counts pre-zeroed).
// ---------------------------------------------------------------------------
__global__ __launch_bounds__(256) void hist_kernel(
    const int* __restrict__ dst, int* __restrict__ counts)
{
    int e = blockIdx.x * 256 + threadIdx.x;
    atomicAdd(&counts[dst[e]], 1);
}

// ---------------------------------------------------------------------------
// Hierarchical scan, 3 phases.
// ---------------------------------------------------------------------------
__global__ __launch_bounds__(256) void scan1_kernel(
    const int* __restrict__ counts, int* __restrict__ blocksum)
{
    const int t = threadIdx.x;
    const int i = blockIdx.x * SCAN_CH + t;
    int v = (i < N_NODES) ? counts[i] : 0;
    #pragma unroll
    for (int off = 32; off > 0; off >>= 1)
        v += __shfl_down(v, off);
    __shared__ int ws[4];
    if ((t & 63) == 0) ws[t >> 6] = v;
    __syncthreads();
    if (t == 0) blocksum[blockIdx.x] = ws[0] + ws[1] + ws[2] + ws[3];
}

__global__ __launch_bounds__(256) void scan2_kernel(
    const int* __restrict__ blocksum, int* __restrict__ blockbase)
{
    __shared__ int s[256];
    const int t = threadIdx.x;
    int v = (t < SCAN_NB) ? blocksum[t] : 0;
    s[t] = v;
    __syncthreads();
    for (int off = 1; off < 256; off <<= 1) {
        int u = (t >= off) ? s[t - off] : 0;
        __syncthreads();
        s[t] += u;
        __syncthreads();
    }
    if (t < SCAN_NB) blockbase[t] = s[t] - v;
}

__global__ __launch_bounds__(256) void scan3_kernel(
    const int* __restrict__ counts, const int* __restrict__ blockbase,
    int* __restrict__ offsets, int* __restrict__ cursor)
{
    __shared__ int s[256];
    const int t = threadIdx.x;
    const int i = blockIdx.x * SCAN_CH + t;
    int v = (i < N_NODES) ? counts[i] : 0;
    s[t] = v;
    __syncthreads();
    for (int off = 1; off < 256; off <<= 1) {
        int u = (t >= off) ? s[t - off] : 0;
        __syncthreads();
        s[t] += u;
        __syncthreads();
    }
    if (i < N_NODES) {
        const int base = blockbase[blockIdx.x];
        const int excl = base + s[t] - v;
        offsets[i] = excl;
        cursor[i]  = excl;
        if (i == N_NODES - 1) offsets[N_NODES] = base + s[t];
    }
}

// ---------------------------------------------------------------------------
// Scatter v3 (= v1 structure + int2 packing): 1 edge/thread for max TLP
// (R6 lesson: intra-thread ILP serializes at low VGPR; latency is hidden by
// wave count).  Writes: 2 x uint4 ea (bf16) + 1 x int2 {src,dst} per edge.
// ---------------------------------------------------------------------------
__global__ __launch_bounds__(256) void scatter_kernel(
    const int* __restrict__ src, const int* __restrict__ dst,
    const float* __restrict__ edge_attr,
    int* __restrict__ cursor, int2* __restrict__ srcdst,
    uint4* __restrict__ sorted_eah)
{
    int e = blockIdx.x * 256 + threadIdx.x;
    int d = dst[e];
    int pos = atomicAdd(&cursor[d], 1);
    srcdst[pos] = make_int2(src[e], d);
    const float4* ea = (const float4*)(edge_attr + (size_t)e * EF);
    float4 a0 = ea[0], a1 = ea[1], a2 = ea[2], a3 = ea[3];
    uint4 o0, o1;
    o0.x = pack_bf2(a0.x, a0.y); o0.y = pack_bf2(a0.z, a0.w);
    o0.z = pack_bf2(a1.x, a1.y); o0.w = pack_bf2(a1.z, a1.w);
    o1.x = pack_bf2(a2.x, a2.y); o1.y = pack_bf2(a2.z, a2.w);
    o1.z = pack_bf2(a3.x, a3.y); o1.w = pack_bf2(a3.z, a3.w);
    sorted_eah[(size_t)pos * 2]     = o0;
    sorted_eah[(size_t)pos * 2 + 1] = o1;
}

// ---------------------------------------------------------------------------
// Graph offsets: batch is sorted; goff[g] = lower_bound(batch, g), goff[512]=N.
// ---------------------------------------------------------------------------
__global__ __launch_bounds__(512) void goff_kernel(
    const int* __restrict__ batch, int* __restrict__ goff)
{
    const int g = threadIdx.x;
    int lo = 0, hi = N_NODES;
    while (lo < hi) {
        int mid = (lo + hi) >> 1;
        if (batch[mid] < g) lo = mid + 1; else hi = mid;
    }
    goff[g] = lo;
    if (g == 0) goff[N_GRAPHS] = N_NODES;
}

// ---------------------------------------------------------------------------
// Weight prep: transpose W1/W2 (all layers) to bf16 Wt[out][k], once per call.
// ---------------------------------------------------------------------------
__global__ __launch_bounds__(256) void wprep_kernel(
    const float* __restrict__ W1, const float* __restrict__ W2,
    unsigned short* __restrict__ Wt)
{
    const int matid = blockIdx.x;          // l*2 + (0:W1, 1:W2)
    const int l = matid >> 1;
    const float* srcm = (matid & 1) ? (W2 + (size_t)l * D * D)
                                    : (W1 + (size_t)l * D * D);
    unsigned short* out = Wt + (size_t)matid * D * D;
    for (int i = 0; i < 64; ++i) {
        int idx = threadIdx.x + i * 256;
        int k = idx >> 7, n = idx & 127;
        out[n * D + k] = f2bf(srcm[idx]);
    }
}

// ---------------------------------------------------------------------------
// elW B-fragment prep (verified): per layer, 8 tiles x 64 lanes x 8 bf16.
// k 0..15 = elW; k16 = elb (bias trick); k17..31 = 0.
// ---------------------------------------------------------------------------
__global__ __launch_bounds__(512) void elprep_kernel(
    const float* __restrict__ elW, const float* __restrict__ elb,
    uint4* __restrict__ elWf)                 // [LAYERS][8][64]
{
    const int l    = blockIdx.x;
    const int t    = threadIdx.x >> 6;
    const int lane = threadIdx.x & 63;
    const int q = lane >> 4, c = lane & 15;
    const float* W = elW + (size_t)l * EF * D;
    unsigned short h[8];
    #pragma unroll
    for (int i = 0; i < 8; ++i) {
        int k = q * 8 + i;
        float v = 0.f;
        if (q < 2)                 v = W[k * D + t * 16 + c];
        else if (q == 2 && i == 0) v = elb[l * D + t * 16 + c];
        h[i] = f2bf(v);
    }
    uint4 o;
    o.x = (u32)h[0] | ((u32)h[1] << 16);
    o.y = (u32)h[2] | ((u32)h[3] << 16);
    o.z = (u32)h[4] | ((u32)h[5] << 16);
    o.w = (u32)h[6] | ((u32)h[7] << 16);
    elWf[((size_t)l * 8 + t) * 64 + lane] = o;
}

// ---------------------------------------------------------------------------
// x -> bf16 (once per call).
// ---------------------------------------------------------------------------
__global__ __launch_bounds__(256) void xprep_kernel(
    const float* __restrict__ x, unsigned short* __restrict__ xb)
{
    int i = blockIdx.x * 256 + threadIdx.x;
    xb[i] = f2bf(x[i]);
}

// ---------------------------------------------------------------------------
// Per-layer aggregation v6 (edge-tiled MFMA, latency-batched phase 2):
//   zin_f[n][:] += sum_{e: dst=n} relu(h[src_e] + ea_e@elW + elb)  (fp32 atomics)
// 4096 waves x contiguous dst-sorted 16-edge chunks. Per chunk:
//   - s_load 16 packed {src,dst} pairs (wave-uniform)
//   - issue 32 coalesced ushort h-gathers (lane owns feats l, l+64)
//   - MFMA E = ea@elW+elb -> per-wave LDS slice (no barriers)
//   - 32 ds_read_b32, conflict-free (lane-linear)
//   - register-only serial segmented accumulate; flush = 2 atomics on
//     dst-change (uniform branch).  (+h[n] self term folded into node_mlp.)
// ---------------------------------------------------------------------------
__global__ __launch_bounds__(256) void aggr_kernel(
    const unsigned short* __restrict__ h_b,    // [N][128] bf16
    const uint4* __restrict__ sorted_ea,       // [E] 2 x uint4 (bf16x16)
    const int*   __restrict__ srcdst,          // [E] packed {src,dst}, dst nondecr.
    const uint4* __restrict__ elWf,            // [8][64] this layer
    float* __restrict__ zin_f)                 // [N][128] f32, pre-zeroed
{
    __shared__ float e_lds_all[AGGR_WPB][16 * ELDS_STR];
    const int tid  = threadIdx.x;
    const int wv   = __builtin_amdgcn_readfirstlane(tid >> 6);
    const int lane = tid & 63;
    const int q    = lane >> 4;
    const int c    = lane & 15;
    const int w    = blockIdx.x * AGGR_WPB + wv;

    float* e_lds = e_lds_all[wv];

    // B fragments (verified layout), L2-resident
    bf16x8 bfr[8];
    #pragma unroll
    for (int t = 0; t < 8; ++t)
        bfr[t] = __builtin_bit_cast(bf16x8, elWf[t * 64 + lane]);

    // A-frag masks: q<2 pass ea; q2 -> k16 = bf16(1.0) bias row; q3 -> 0
    const u32 mand = (q < 2) ? 0xFFFFFFFFu : 0u;
    const u32 mor0 = (q == 2) ? 0x3F80u : 0u;

    const int qc = NCHUNK / NWAVES, rc = NCHUNK % NWAVES;
    const int c0 = w * qc + (w < rc ? w : rc);
    const int cn = qc + (w < rc ? 1 : 0);
    const int e_lo = c0 * 16;
    const int e_hi = (c0 + cn) * 16;

    int cur = srcdst[(size_t)e_lo * 2 + 1];   // first dst, wave-uniform
    float accA = 0.f, accB = 0.f;
    const f32x4 zero4 = (f32x4){0.f, 0.f, 0.f, 0.f};

#define HLOAD(I, SV)                                                          \
    const u32 hA##I = h_b[(size_t)(SV) * D + lane];                           \
    const u32 hB##I = h_b[(size_t)(SV) * D + 64 + lane];

#define EREAD(I)                                                              \
    const float eA##I = e_lds[(I) * ELDS_STR + lane];                         \
    const float eB##I = e_lds[(I) * ELDS_STR + 64 + lane];

#define ACC(I, DV)                                                            \
    {                                                                         \
        if ((DV) != cur) {                                                    \
            atomicAdd(&zin_f[(size_t)cur * D + lane],      accA);             \
            atomicAdd(&zin_f[(size_t)cur * D + 64 + lane], accB);             \
            accA = 0.f; accB = 0.f; cur = (DV);                               \
        }                                                                     \
        accA += fmaxf(eA##I + bf2f((unsigned short)hA##I), 0.f);              \
        accB += fmaxf(eB##I + bf2f((unsigned short)hB##I), 0.f);              \
    }

    for (int e0 = e_lo; e0 < e_hi; e0 += 16) {
        // --- wave-uniform packed ids: 8 x int4 = (s,d,s,d) ---
        const int4* sp = (const int4*)(srcdst + (size_t)e0 * 2);
        const int4 p0 = sp[0], p1 = sp[1], p2 = sp[2], p3 = sp[3];
        const int4 p4 = sp[4], p5 = sp[5], p6 = sp[6], p7 = sp[7];

        // --- issue all 32 coalesced h gathers (latency hides under MFMA) ---
        HLOAD(0,  p0.x) HLOAD(1,  p0.z) HLOAD(2,  p1.x) HLOAD(3,  p1.z)
        HLOAD(4,  p2.x) HLOAD(5,  p2.z) HLOAD(6,  p3.x) HLOAD(7,  p3.z)
        HLOAD(8,  p4.x) HLOAD(9,  p4.z) HLOAD(10, p5.x) HLOAD(11, p5.z)
        HLOAD(12, p6.x) HLOAD(13, p6.z) HLOAD(14, p7.x) HLOAD(15, p7.z)

        // --- phase 1: E = ea@elW + elb -> LDS (f32) ---
        uint4 araw = sorted_ea[(size_t)(e0 + c) * 2 + (q & 1)];
        uint4 aw;
        aw.x = (araw.x & mand) | mor0;
        aw.y =  araw.y & mand;
        aw.z =  araw.z & mand;
        aw.w =  araw.w & mand;
        const bf16x8 afr = __builtin_bit_cast(bf16x8, aw);

        #pragma unroll
        for (int t = 0; t < 8; ++t) {
            f32x4 C = __builtin_amdgcn_mfma_f32_16x16x32_bf16(
                afr, bfr[t], zero4, 0, 0, 0);
            #pragma unroll
            for (int rr = 0; rr < 4; ++rr)
                e_lds[(q * 4 + rr) * ELDS_STR + t * 16 + c] = C[rr];
        }
        // same-wave LDS RAW: compiler inserts lgkmcnt waits

        // --- batch-read all 32 E values (conflict-free b32) ---
        EREAD(0)  EREAD(1)  EREAD(2)  EREAD(3)
        EREAD(4)  EREAD(5)  EREAD(6)  EREAD(7)
        EREAD(8)  EREAD(9)  EREAD(10) EREAD(11)
        EREAD(12) EREAD(13) EREAD(14) EREAD(15)

        // --- register-only serial segmented accumulate ---
        ACC(0,  p0.y) ACC(1,  p0.w) ACC(2,  p1.y) ACC(3,  p1.w)
        ACC(4,  p2.y) ACC(5,  p2.w) ACC(6,  p3.y) ACC(7,  p3.w)
        ACC(8,  p4.y) ACC(9,  p4.w) ACC(10, p5.y) ACC(11, p5.w)
        ACC(12, p6.y) ACC(13, p6.w) ACC(14, p7.y) ACC(15, p7.w)
    }
#undef HLOAD
#undef EREAD
#undef ACC

    atomicAdd(&zin_f[(size_t)cur * D + lane],      accA);
    atomicAdd(&zin_f[(size_t)cur * D + 64 + lane], accB);
}

// ---------------------------------------------------------------------------
// Fused node MLP via MFMA (bf16 in, fp32 accumulate):
//   hout_b = bf16(relu(relu(BN((h+zin_f)@W1+b1))@W2 + b2))
// The +h and f32->bf16 of the aggregation are folded into the A-frag load.
// In-place h update is safe: each block reads/writes only its own 64 rows.
// ---------------------------------------------------------------------------
__global__ __launch_bounds__(128) void node_mlp(
    const float* __restrict__ zin_f,            // [N][128] f32 (aggr sums)
    const unsigned short* __restrict__ h_in,    // [N][128] bf16 (layer input)
    const unsigned short* __restrict__ W1t,     // [128 out][128 k] bf16
    const float* __restrict__ b1,
    const float* __restrict__ bng, const float* __restrict__ bnb,
    const float* __restrict__ bnm, const float* __restrict__ bnv,
    const unsigned short* __restrict__ W2t,
    const float* __restrict__ b2,
    unsigned short* __restrict__ hout_b)
{
    __shared__ unsigned short zmid[64 * 136];   // 17.4 KB
    __shared__ float scale_s[128], shift_s[128], b2_s[128];

    const int tid  = threadIdx.x;
    const int wv   = tid >> 6;
    const int lane = tid & 63;
    const int q    = lane >> 4;
    const int m    = lane & 15;
    const int node0 = blockIdx.x * 64;

    {
        float sc = bng[tid] * rsqrtf(bnv[tid] + BN_EPS);
        scale_s[tid] = sc;
        shift_s[tid] = b1[tid] * sc + bnb[tid] - bnm[tid] * sc;
        b2_s[tid]    = b2[tid];
    }

    // A fragments: bf16(h + zin_f)
    bf16x8 a[2][4];
    #pragma unroll
    for (int sub = 0; sub < 2; ++sub) {
        int node = node0 + wv * 32 + sub * 16 + m;
        if (node >= N_NODES) node = N_NODES - 1;
        const float* zr = zin_f + (size_t)node * D;
        const unsigned short* hr = h_in + (size_t)node * D;
        #pragma unroll
        for (int kk = 0; kk < 4; ++kk) {
            const int base = kk * 32 + q * 8;
            float4 z0 = *(const float4*)(zr + base);
            float4 z1 = *(const float4*)(zr + base + 4);
            uint4  hv = *(const uint4*)(hr + base);
            bf16x8 t;
            t[0] = (short)f2bf(z0.x + lo16f(hv.x));
            t[1] = (short)f2bf(z0.y + hi16f(hv.x));
            t[2] = (short)f2bf(z0.z + lo16f(hv.y));
            t[3] = (short)f2bf(z0.w + hi16f(hv.y));
            t[4] = (short)f2bf(z1.x + lo16f(hv.z));
            t[5] = (short)f2bf(z1.y + hi16f(hv.z));
            t[6] = (short)f2bf(z1.z + lo16f(hv.w));
            t[7] = (short)f2bf(z1.w + hi16f(hv.w));
            a[sub][kk] = t;
        }
    }

    f32x4 acc[2][8];
    #pragma unroll
    for (int s2 = 0; s2 < 2; ++s2)
        #pragma unroll
        for (int t = 0; t < 8; ++t)
            acc[s2][t] = (f32x4){0.f, 0.f, 0.f, 0.f};

    __syncthreads();

    #pragma unroll
    for (int t = 0; t < 8; ++t) {
        const unsigned short* wrow = W1t + (size_t)(t * 16 + m) * D;
        bf16x8 bfr[4];
        #pragma unroll
        for (int k = 0; k < 4; ++k)
            bfr[k] = __builtin_bit_cast(bf16x8, *(const uint4*)&wrow[k * 32 + q * 8]);
        #pragma unroll
        for (int sub = 0; sub < 2; ++sub) {
            acc[sub][t] = __builtin_amdgcn_mfma_f32_16x16x32_bf16(a[sub][0], bfr[0], acc[sub][t], 0, 0, 0);
            acc[sub][t] = __builtin_amdgcn_mfma_f32_16x16x32_bf16(a[sub][1], bfr[1], acc[sub][t], 0, 0, 0);
            acc[sub][t] = __builtin_amdgcn_mfma_f32_16x16x32_bf16(a[sub][2], bfr[2], acc[sub][t], 0, 0, 0);
            acc[sub][t] = __builtin_amdgcn_mfma_f32_16x16x32_bf16(a[sub][3], bfr[3], acc[sub][t], 0, 0, 0);
        }
    }

    #pragma unroll
    for (int sub = 0; sub < 2; ++sub)
        #pragma unroll
        for (int t = 0; t < 8; ++t) {
            int col = t * 16 + m;
            float sc = scale_s[col], sh = shift_s[col];
            #pragma unroll
            for (int rr = 0; rr < 4; ++rr) {
                float v = fmaxf(acc[sub][t][rr] * sc + sh, 0.f);
                int row = wv * 32 + sub * 16 + q * 4 + rr;
                zmid[row * 136 + col] = f2bf(v);
            }
        }

    __syncthreads();

    bf16x8 a2[2][4];
    #pragma unroll
    for (int sub = 0; sub < 2; ++sub) {
        const unsigned short* zr = &zmid[(wv * 32 + sub * 16 + m) * 136];
        #pragma unroll
        for (int k = 0; k < 4; ++k)
            a2[sub][k] = __builtin_bit_cast(bf16x8, *(const uint4*)&zr[k * 32 + q * 8]);
    }

    #pragma unroll
    for (int s2 = 0; s2 < 2; ++s2)
        #pragma unroll
        for (int t = 0; t < 8; ++t)
            acc[s2][t] = (f32x4){0.f, 0.f, 0.f, 0.f};

    #pragma unroll
    for (int t = 0; t < 8; ++t) {
        const unsigned short* wrow = W2t + (size_t)(t * 16 + m) * D;
        bf16x8 bfr[4];
        #pragma unroll
        for (int k = 0; k < 4; ++k)
            bfr[k] = __builtin_bit_cast(bf16x8, *(const uint4*)&wrow[k * 32 + q * 8]);
        #pragma unroll
        for (int sub = 0; sub < 2; ++sub) {
            acc[sub][t] = __builtin_amdgcn_mfma_f32_16x16x32_bf16(a2[sub][0], bfr[0], acc[sub][t], 0, 0, 0);
            acc[sub][t] = __builtin_amdgcn_mfma_f32_16x16x32_bf16(a2[sub][1], bfr[1], acc[sub][t], 0, 0, 0);
            acc[sub][t] = __builtin_amdgcn_mfma_f32_16x16x32_bf16(a2[sub][2], bfr[2], acc[sub][t], 0, 0, 0);
            acc[sub][t] = __builtin_amdgcn_mfma_f32_16x16x32_bf16(a2[sub][3], bfr[3], acc[sub][t], 0, 0, 0);
        }
    }

    #pragma unroll
    for (int sub = 0; sub < 2; ++sub)
        #pragma unroll
        for (int rr = 0; rr < 4; ++rr) {
            int node = node0 + wv * 32 + sub * 16 + q * 4 + rr;
            if (node < N_NODES) {
                unsigned short* hrow = hout_b + (size_t)node * D;
                #pragma unroll
                for (int t = 0; t < 8; ++t) {
                    int col = t * 16 + m;
                    hrow[col] = f2bf(fmaxf(acc[sub][t][rr] + b2_s[col], 0.f));
                }
            }
        }
}

// ---------------------------------------------------------------------------
// Pool v2: segmented sum over sorted batch (bf16 in, fp32 out).
// u32 loads (2 feats/thread), 8-way row split + LDS combine. No atomics.
// ---------------------------------------------------------------------------
__global__ __launch_bounds__(512) void pool_kernel(
    const unsigned short* __restrict__ hout_b, const int* __restrict__ goff,
    float* __restrict__ pool, int layer_off)
{
    __shared__ float2 part[7][64];
    const int g   = blockIdx.x;
    const int j2  = threadIdx.x & 63;      // owns feats 2*j2, 2*j2+1
    const int grp = threadIdx.x >> 6;      // 0..7
    const int beg = goff[g], end = goff[g + 1];
    const int len = end - beg;
    const int ch  = (len + 7) >> 3;
    int lo = beg + grp * ch;
    int hi = lo + ch;
    if (hi > end) hi = end;
    float ax = 0.f, ay = 0.f;
    for (int r = lo; r < hi; ++r) {
        const u32 v = *(const u32*)(hout_b + (size_t)r * D + 2 * j2);
        ax += lo16f(v);
        ay += hi16f(v);
    }
    if (grp) part[grp - 1][j2] = make_float2(ax, ay);
    __syncthreads();
    if (grp == 0) {
        #pragma unroll
        for (int i = 0; i < 7; ++i) {
            float2 p = part[i][j2];
            ax += p.x; ay += p.y;
        }
        *(float2*)(pool + g * (LAYERS * D) + layer_off + 2 * j2) =
            make_float2(ax, ay);
    }
}

// ---------------------------------------------------------------------------
// Head: out[g] = relu(pool[g] @ lin1_W + lin1_b) @ lin2_W + lin2_b
// ---------------------------------------------------------------------------
__global__ __launch_bounds__(384) void head_kernel(
    const float* __restrict__ pool,
    const float* __restrict__ lin1W,
    const float* __restrict__ lin1b,
    const float* __restrict__ lin2W,
    const float* __restrict__ lin2b,
    float*       __restrict__ out)
{
    __shared__ float gs[LAYERS * D];
    __shared__ float red[LAYERS * D];
    const int g   = blockIdx.x;
    const int tid = threadIdx.x;
    gs[tid] = pool[g * (LAYERS * D) + tid];
    __syncthreads();

    float acc = lin1b[tid];
    #pragma unroll 4
    for (int k = 0; k < LAYERS * D; ++k)
        acc = fmaf(gs[k], lin1W[k * (LAYERS * D) + tid], acc);
    acc = fmaxf(acc, 0.0f);
    float p = acc * lin2W[tid];

    red[tid] = p;
    __syncthreads();
    if (tid < 128) red[tid] = red[tid] + red[tid + 128] + red[tid + 256];
    __syncthreads();
    if (tid < 64) {
        float v = red[tid] + red[tid + 64];
        v += __shfl_down(v, 32);
        v += __shfl_down(v, 16);
        v += __shfl_down(v, 8);
        v += __shfl_down(v, 4);
        v += __shfl_down(v, 2);
        v += __shfl_down(v, 1);
        if (tid == 0) out[g] = v + lin2b[0];
    }
}

// ---------------------------------------------------------------------------
extern "C" void kernel_launch(void* const* d_in, const int* in_sizes, int n_in,
                              void* d_out, int out_size, void* d_ws, size_t ws_size,
                              hipStream_t stream)
{
    const float* x         = (const float*)d_in[0];
    const float* edge_attr = (const float*)d_in[1];
    const float* elW       = (const float*)d_in[2];
    const float* elb       = (const float*)d_in[3];
    const float* W1        = (const float*)d_in[4];
    const float* b1        = (const float*)d_in[5];
    const float* bn_g      = (const float*)d_in[6];
    const float* bn_b      = (const float*)d_in[7];
    const float* bn_mean   = (const float*)d_in[8];
    const float* bn_var    = (const float*)d_in[9];
    const float* W2        = (const float*)d_in[10];
    const float* b2        = (const float*)d_in[11];
    const float* lin1W     = (const float*)d_in[12];
    const float* lin1b     = (const float*)d_in[13];
    const float* lin2W     = (const float*)d_in[14];
    const float* lin2b     = (const float*)d_in[15];
    const int*   ei        = (const int*)d_in[16];
    const int*   batch     = (const int*)d_in[17];
    const int*   src = ei;
    const int*   dst = ei + N_EDGES;

    // Workspace layout, all 16B-aligned:
    float*          pool       = (float*)d_ws;                              // G*384 f32
    unsigned short* xb         = (unsigned short*)(pool + (size_t)N_GRAPHS * LAYERS * D);
    unsigned short* hA_b       = xb   + (size_t)N_NODES * D;                // bf16
    float*          zin_f      = (float*)(hA_b + (size_t)N_NODES * D);      // [N][128] f32
    unsigned short* Wt         = (unsigned short*)(zin_f + (size_t)N_NODES * D);
    uint4*          elWf       = (uint4*)(Wt + 6 * D * D);                  // 3*8*64 uint4
    u32*            sorted_eah = (u32*)(elWf + LAYERS * 8 * 64);            // E*8 u32
    int*            srcdst     = (int*)(sorted_eah + (size_t)N_EDGES * 8);  // E int2
    int*            counts     = srcdst + (size_t)N_EDGES * 2;
    int*            offsets    = counts + N_NODES;                          // N+1
    int*            cursor     = offsets + N_NODES + 4;
    int*            goff       = cursor + N_NODES + 4;                      // 513 ints
    int*            blocksum   = goff + N_GRAPHS + 4;
    int*            blockbase  = blocksum + SCAN_NB + 4;

    hipMemsetAsync(counts, 0, (size_t)N_NODES * sizeof(int), stream);

    // --- once-per-call prep ---
    wprep_kernel<<<6, 256, 0, stream>>>(W1, W2, Wt);
    elprep_kernel<<<LAYERS, 512, 0, stream>>>(elW, elb, elWf);
    xprep_kernel<<<(N_NODES * D) / 256, 256, 0, stream>>>(x, xb);
    goff_kernel<<<1, 512, 0, stream>>>(batch, goff);
    hist_kernel<<<N_EDGES / 256, 256, 0, stream>>>(dst, counts);
    scan1_kernel<<<SCAN_NB, 256, 0, stream>>>(counts, blocksum);
    scan2_kernel<<<1, 256, 0, stream>>>(blocksum, blockbase);
    scan3_kernel<<<SCAN_NB, 256, 0, stream>>>(counts, blockbase, offsets, cursor);
    scatter_kernel<<<N_EDGES / 256, 256, 0, stream>>>(
        src, dst, edge_attr, cursor, (int2*)srcdst, (uint4*)sorted_eah);

    const unsigned short* hin_b = xb;
    for (int l = 0; l < LAYERS; ++l) {
        hipMemsetAsync(zin_f, 0, (size_t)N_NODES * D * sizeof(float), stream);
        aggr_kernel<<<AGGR_BLK, 256, 0, stream>>>(
            hin_b, (const uint4*)sorted_eah, srcdst,
            elWf + (size_t)l * 8 * 64, zin_f);
        node_mlp<<<(N_NODES + 63) / 64, 128, 0, stream>>>(
            zin_f, hin_b,
            Wt + (size_t)(l * 2)     * D * D, b1 + l * D,
            bn_g + l * D, bn_b + l * D, bn_mean + l * D, bn_var + l * D,
            Wt + (size_t)(l * 2 + 1) * D * D, b2 + l * D,
            hA_b);
        pool_kernel<<<N_GRAPHS, 512, 0, stream>>>(hA_b, goff, pool, l * D);
        hin_b = hA_b;
    }

    head_kernel<<<N_GRAPHS, LAYERS * D, 0, stream>>>(
        pool, lin1W, lin1b, lin2W, lin2b, (float*)d_out);
}

// Round 8
// 769.085 us; speedup vs baseline: 1.0815x; 1.0243x over previous
//
#include <hip/hip_runtime.h>

#define N_NODES   50000
#define N_EDGES   1600000
#define N_GRAPHS  512
#define LAYERS    3
#define D         128
#define EF        16
#define BN_EPS    1e-5f

#define SCAN_CH   256
#define SCAN_NB   ((N_NODES + SCAN_CH - 1) / SCAN_CH)   // 196

#define NCHUNK    (N_EDGES / 16)        // 100000 (E % 16 == 0)
#define AGGR_BLK  2048
#define AGGR_WPB  2
#define NWAVES    (AGGR_BLK * AGGR_WPB) // 4096
#define ELDS_STR  130                   // dwords: 2-way (free) write banks

typedef unsigned int u32;
typedef short bf16x8 __attribute__((ext_vector_type(8)));
typedef float f32x4 __attribute__((ext_vector_type(4)));

__device__ __forceinline__ unsigned short f2bf(float f) {   // RNE f32->bf16
    unsigned u = __builtin_bit_cast(unsigned, f);
    u += 0x7FFF + ((u >> 16) & 1);
    return (unsigned short)(u >> 16);
}

__device__ __forceinline__ float bf2f(unsigned short u) {
    return __builtin_bit_cast(float, (unsigned)u << 16);
}

__device__ __forceinline__ float lo16f(u32 u) {
    return __builtin_bit_cast(float, u << 16);
}
__device__ __forceinline__ float hi16f(u32 u) {
    return __builtin_bit_cast(float, u & 0xFFFF0000u);
}

__device__ __forceinline__ u32 pack_bf2(float x, float y) {
    return ((u32)f2bf(x)) | ((u32)f2bf(y) << 16);
}

// ---------------------------------------------------------------------------
// CSR build step 1: histogram of dst (counts pre-zeroed).
// ---------------------------------------------------------------------------
__global__ __launch_bounds__(256) void hist_kernel(
    const int* __restrict__ dst, int* __restrict__ counts)
{
    int e = blockIdx.x * 256 + threadIdx.x;
    atomicAdd(&counts[dst[e]], 1);
}

// ---------------------------------------------------------------------------
// Hierarchical scan, 3 phases.
// ---------------------------------------------------------------------------
__global__ __launch_bounds__(256) void scan1_kernel(
    const int* __restrict__ counts, int* __restrict__ blocksum)
{
    const int t = threadIdx.x;
    const int i = blockIdx.x * SCAN_CH + t;
    int v = (i < N_NODES) ? counts[i] : 0;
    #pragma unroll
    for (int off = 32; off > 0; off >>= 1)
        v += __shfl_down(v, off);
    __shared__ int ws[4];
    if ((t & 63) == 0) ws[t >> 6] = v;
    __syncthreads();
    if (t == 0) blocksum[blockIdx.x] = ws[0] + ws[1] + ws[2] + ws[3];
}

__global__ __launch_bounds__(256) void scan2_kernel(
    const int* __restrict__ blocksum, int* __restrict__ blockbase)
{
    __shared__ int s[256];
    const int t = threadIdx.x;
    int v = (t < SCAN_NB) ? blocksum[t] : 0;
    s[t] = v;
    __syncthreads();
    for (int off = 1; off < 256; off <<= 1) {
        int u = (t >= off) ? s[t - off] : 0;
        __syncthreads();
        s[t] += u;
        __syncthreads();
    }
    if (t < SCAN_NB) blockbase[t] = s[t] - v;
}

__global__ __launch_bounds__(256) void scan3_kernel(
    const int* __restrict__ counts, const int* __restrict__ blockbase,
    int* __restrict__ offsets, int* __restrict__ cursor)
{
    __shared__ int s[256];
    const int t = threadIdx.x;
    const int i = blockIdx.x * SCAN_CH + t;
    int v = (i < N_NODES) ? counts[i] : 0;
    s[t] = v;
    __syncthreads();
    for (int off = 1; off < 256; off <<= 1) {
        int u = (t >= off) ? s[t - off] : 0;
        __syncthreads();
        s[t] += u;
        __syncthreads();
    }
    if (i < N_NODES) {
        const int base = blockbase[blockIdx.x];
        const int excl = base + s[t] - v;
        offsets[i] = excl;
        cursor[i]  = excl;
        if (i == N_NODES - 1) offsets[N_NODES] = base + s[t];
    }
}

// ---------------------------------------------------------------------------
// Scatter v3: 1 edge/thread for max TLP (R6 lesson: intra-thread ILP
// serializes; latency is hidden by wave count).  Writes per edge:
// 2 x uint4 ea (bf16) + 1 x int2 {src,dst}.
// ---------------------------------------------------------------------------
__global__ __launch_bounds__(256) void scatter_kernel(
    const int* __restrict__ src, const int* __restrict__ dst,
    const float* __restrict__ edge_attr,
    int* __restrict__ cursor, int2* __restrict__ srcdst,
    uint4* __restrict__ sorted_eah)
{
    int e = blockIdx.x * 256 + threadIdx.x;
    int d = dst[e];
    int pos = atomicAdd(&cursor[d], 1);
    srcdst[pos] = make_int2(src[e], d);
    const float4* ea = (const float4*)(edge_attr + (size_t)e * EF);
    float4 a0 = ea[0], a1 = ea[1], a2 = ea[2], a3 = ea[3];
    uint4 o0, o1;
    o0.x = pack_bf2(a0.x, a0.y); o0.y = pack_bf2(a0.z, a0.w);
    o0.z = pack_bf2(a1.x, a1.y); o0.w = pack_bf2(a1.z, a1.w);
    o1.x = pack_bf2(a2.x, a2.y); o1.y = pack_bf2(a2.z, a2.w);
    o1.z = pack_bf2(a3.x, a3.y); o1.w = pack_bf2(a3.z, a3.w);
    sorted_eah[(size_t)pos * 2]     = o0;
    sorted_eah[(size_t)pos * 2 + 1] = o1;
}

// ---------------------------------------------------------------------------
// Graph offsets: batch is sorted; goff[g] = lower_bound(batch, g), goff[512]=N.
// ---------------------------------------------------------------------------
__global__ __launch_bounds__(512) void goff_kernel(
    const int* __restrict__ batch, int* __restrict__ goff)
{
    const int g = threadIdx.x;
    int lo = 0, hi = N_NODES;
    while (lo < hi) {
        int mid = (lo + hi) >> 1;
        if (batch[mid] < g) lo = mid + 1; else hi = mid;
    }
    goff[g] = lo;
    if (g == 0) goff[N_GRAPHS] = N_NODES;
}

// ---------------------------------------------------------------------------
// Weight prep: transpose W1/W2 (all layers) to bf16 Wt[out][k], once per call.
// ---------------------------------------------------------------------------
__global__ __launch_bounds__(256) void wprep_kernel(
    const float* __restrict__ W1, const float* __restrict__ W2,
    unsigned short* __restrict__ Wt)
{
    const int matid = blockIdx.x;          // l*2 + (0:W1, 1:W2)
    const int l = matid >> 1;
    const float* srcm = (matid & 1) ? (W2 + (size_t)l * D * D)
                                    : (W1 + (size_t)l * D * D);
    unsigned short* out = Wt + (size_t)matid * D * D;
    for (int i = 0; i < 64; ++i) {
        int idx = threadIdx.x + i * 256;
        int k = idx >> 7, n = idx & 127;
        out[n * D + k] = f2bf(srcm[idx]);
    }
}

// ---------------------------------------------------------------------------
// elW B-fragment prep (verified): per layer, 8 tiles x 64 lanes x 8 bf16.
// k 0..15 = elW; k16 = elb (bias trick); k17..31 = 0.
// ---------------------------------------------------------------------------
__global__ __launch_bounds__(512) void elprep_kernel(
    const float* __restrict__ elW, const float* __restrict__ elb,
    uint4* __restrict__ elWf)                 // [LAYERS][8][64]
{
    const int l    = blockIdx.x;
    const int t    = threadIdx.x >> 6;
    const int lane = threadIdx.x & 63;
    const int q = lane >> 4, c = lane & 15;
    const float* W = elW + (size_t)l * EF * D;
    unsigned short h[8];
    #pragma unroll
    for (int i = 0; i < 8; ++i) {
        int k = q * 8 + i;
        float v = 0.f;
        if (q < 2)                 v = W[k * D + t * 16 + c];
        else if (q == 2 && i == 0) v = elb[l * D + t * 16 + c];
        h[i] = f2bf(v);
    }
    uint4 o;
    o.x = (u32)h[0] | ((u32)h[1] << 16);
    o.y = (u32)h[2] | ((u32)h[3] << 16);
    o.z = (u32)h[4] | ((u32)h[5] << 16);
    o.w = (u32)h[6] | ((u32)h[7] << 16);
    elWf[((size_t)l * 8 + t) * 64 + lane] = o;
}

// ---------------------------------------------------------------------------
// x -> bf16 (once per call).
// ---------------------------------------------------------------------------
__global__ __launch_bounds__(256) void xprep_kernel(
    const float* __restrict__ x, unsigned short* __restrict__ xb)
{
    int i = blockIdx.x * 256 + threadIdx.x;
    xb[i] = f2bf(x[i]);
}

// ---------------------------------------------------------------------------
// Per-layer aggregation v6.1 (edge-tiled MFMA, latency-batched phase 2).
// 128-thr blocks (2 waves, 16.6 KB LDS) -> 9 blocks/CU, 18 waves/CU.
// Per 16-edge chunk: s_load packed ids; 32 coalesced ushort h-gathers;
// MFMA E=ea@elW+elb -> per-wave LDS; 32 conflict-free b32 reads;
// register-only segmented accumulate; atomics on dst-change.
// ---------------------------------------------------------------------------
__global__ __launch_bounds__(128) void aggr_kernel(
    const unsigned short* __restrict__ h_b,    // [N][128] bf16
    const uint4* __restrict__ sorted_ea,       // [E] 2 x uint4 (bf16x16)
    const int*   __restrict__ srcdst,          // [E] packed {src,dst}, dst nondecr.
    const uint4* __restrict__ elWf,            // [8][64] this layer
    float* __restrict__ zin_f)                 // [N][128] f32, pre-zeroed
{
    __shared__ float e_lds_all[AGGR_WPB][16 * ELDS_STR];
    const int tid  = threadIdx.x;
    const int wv   = __builtin_amdgcn_readfirstlane(tid >> 6);
    const int lane = tid & 63;
    const int q    = lane >> 4;
    const int c    = lane & 15;
    const int w    = blockIdx.x * AGGR_WPB + wv;

    float* e_lds = e_lds_all[wv];

    // B fragments (verified layout), L2-resident
    bf16x8 bfr[8];
    #pragma unroll
    for (int t = 0; t < 8; ++t)
        bfr[t] = __builtin_bit_cast(bf16x8, elWf[t * 64 + lane]);

    // A-frag masks: q<2 pass ea; q2 -> k16 = bf16(1.0) bias row; q3 -> 0
    const u32 mand = (q < 2) ? 0xFFFFFFFFu : 0u;
    const u32 mor0 = (q == 2) ? 0x3F80u : 0u;

    const int qc = NCHUNK / NWAVES, rc = NCHUNK % NWAVES;
    const int c0 = w * qc + (w < rc ? w : rc);
    const int cn = qc + (w < rc ? 1 : 0);
    const int e_lo = c0 * 16;
    const int e_hi = (c0 + cn) * 16;

    int cur = srcdst[(size_t)e_lo * 2 + 1];   // first dst, wave-uniform
    float accA = 0.f, accB = 0.f;
    const f32x4 zero4 = (f32x4){0.f, 0.f, 0.f, 0.f};

#define HLOAD(I, SV)                                                          \
    const u32 hA##I = h_b[(size_t)(SV) * D + lane];                           \
    const u32 hB##I = h_b[(size_t)(SV) * D + 64 + lane];

#define EREAD(I)                                                              \
    const float eA##I = e_lds[(I) * ELDS_STR + lane];                         \
    const float eB##I = e_lds[(I) * ELDS_STR + 64 + lane];

#define ACC(I, DV)                                                            \
    {                                                                         \
        if ((DV) != cur) {                                                    \
            atomicAdd(&zin_f[(size_t)cur * D + lane],      accA);             \
            atomicAdd(&zin_f[(size_t)cur * D + 64 + lane], accB);             \
            accA = 0.f; accB = 0.f; cur = (DV);                               \
        }                                                                     \
        accA += fmaxf(eA##I + bf2f((unsigned short)hA##I), 0.f);              \
        accB += fmaxf(eB##I + bf2f((unsigned short)hB##I), 0.f);              \
    }

    for (int e0 = e_lo; e0 < e_hi; e0 += 16) {
        // --- wave-uniform packed ids: 8 x int4 = (s,d,s,d) ---
        const int4* sp = (const int4*)(srcdst + (size_t)e0 * 2);
        const int4 p0 = sp[0], p1 = sp[1], p2 = sp[2], p3 = sp[3];
        const int4 p4 = sp[4], p5 = sp[5], p6 = sp[6], p7 = sp[7];

        // --- issue all 32 coalesced h gathers (latency hides under MFMA) ---
        HLOAD(0,  p0.x) HLOAD(1,  p0.z) HLOAD(2,  p1.x) HLOAD(3,  p1.z)
        HLOAD(4,  p2.x) HLOAD(5,  p2.z) HLOAD(6,  p3.x) HLOAD(7,  p3.z)
        HLOAD(8,  p4.x) HLOAD(9,  p4.z) HLOAD(10, p5.x) HLOAD(11, p5.z)
        HLOAD(12, p6.x) HLOAD(13, p6.z) HLOAD(14, p7.x) HLOAD(15, p7.z)

        // --- phase 1: E = ea@elW + elb -> LDS (f32) ---
        uint4 araw = sorted_ea[(size_t)(e0 + c) * 2 + (q & 1)];
        uint4 aw;
        aw.x = (araw.x & mand) | mor0;
        aw.y =  araw.y & mand;
        aw.z =  araw.z & mand;
        aw.w =  araw.w & mand;
        const bf16x8 afr = __builtin_bit_cast(bf16x8, aw);

        #pragma unroll
        for (int t = 0; t < 8; ++t) {
            f32x4 C = __builtin_amdgcn_mfma_f32_16x16x32_bf16(
                afr, bfr[t], zero4, 0, 0, 0);
            #pragma unroll
            for (int rr = 0; rr < 4; ++rr)
                e_lds[(q * 4 + rr) * ELDS_STR + t * 16 + c] = C[rr];
        }
        // same-wave LDS RAW: compiler inserts lgkmcnt waits

        // --- batch-read all 32 E values (conflict-free b32) ---
        EREAD(0)  EREAD(1)  EREAD(2)  EREAD(3)
        EREAD(4)  EREAD(5)  EREAD(6)  EREAD(7)
        EREAD(8)  EREAD(9)  EREAD(10) EREAD(11)
        EREAD(12) EREAD(13) EREAD(14) EREAD(15)

        // --- register-only serial segmented accumulate ---
        ACC(0,  p0.y) ACC(1,  p0.w) ACC(2,  p1.y) ACC(3,  p1.w)
        ACC(4,  p2.y) ACC(5,  p2.w) ACC(6,  p3.y) ACC(7,  p3.w)
        ACC(8,  p4.y) ACC(9,  p4.w) ACC(10, p5.y) ACC(11, p5.w)
        ACC(12, p6.y) ACC(13, p6.w) ACC(14, p7.y) ACC(15, p7.w)
    }
#undef HLOAD
#undef EREAD
#undef ACC

    atomicAdd(&zin_f[(size_t)cur * D + lane],      accA);
    atomicAdd(&zin_f[(size_t)cur * D + 64 + lane], accB);
}

// ---------------------------------------------------------------------------
// Fused node MLP via MFMA (bf16 in, fp32 accumulate):
//   hout_b = bf16(relu(relu(BN((h+zin_f)@W1+b1))@W2 + b2))
// +h and f32->bf16 folded into the A-frag load.  If zero_self, each thread
// re-zeroes EXACTLY the zin addresses it loaded (placed after GEMM1, so the
// loads are provably consumed) -> replaces the per-layer zin memset.
// Clamped tail threads skip zeroing (their row is owned by another thread).
// ---------------------------------------------------------------------------
__global__ __launch_bounds__(128) void node_mlp(
    float* __restrict__ zin_f,                  // [N][128] f32 (aggr sums)
    const unsigned short* __restrict__ h_in,    // [N][128] bf16 (layer input)
    const unsigned short* __restrict__ W1t,     // [128 out][128 k] bf16
    const float* __restrict__ b1,
    const float* __restrict__ bng, const float* __restrict__ bnb,
    const float* __restrict__ bnm, const float* __restrict__ bnv,
    const unsigned short* __restrict__ W2t,
    const float* __restrict__ b2,
    unsigned short* __restrict__ hout_b,
    const int zero_self)
{
    __shared__ unsigned short zmid[64 * 136];   // 17.4 KB
    __shared__ float scale_s[128], shift_s[128], b2_s[128];

    const int tid  = threadIdx.x;
    const int wv   = tid >> 6;
    const int lane = tid & 63;
    const int q    = lane >> 4;
    const int m    = lane & 15;
    const int node0 = blockIdx.x * 64;

    {
        float sc = bng[tid] * rsqrtf(bnv[tid] + BN_EPS);
        scale_s[tid] = sc;
        shift_s[tid] = b1[tid] * sc + bnb[tid] - bnm[tid] * sc;
        b2_s[tid]    = b2[tid];
    }

    // A fragments: bf16(h + zin_f)
    bf16x8 a[2][4];
    bool live[2];
    #pragma unroll
    for (int sub = 0; sub < 2; ++sub) {
        int node = node0 + wv * 32 + sub * 16 + m;
        live[sub] = node < N_NODES;
        if (!live[sub]) node = N_NODES - 1;
        const float* zr = zin_f + (size_t)node * D;
        const unsigned short* hr = h_in + (size_t)node * D;
        #pragma unroll
        for (int kk = 0; kk < 4; ++kk) {
            const int base = kk * 32 + q * 8;
            float4 z0 = *(const float4*)(zr + base);
            float4 z1 = *(const float4*)(zr + base + 4);
            uint4  hv = *(const uint4*)(hr + base);
            bf16x8 t;
            t[0] = (short)f2bf(z0.x + lo16f(hv.x));
            t[1] = (short)f2bf(z0.y + hi16f(hv.x));
            t[2] = (short)f2bf(z0.z + lo16f(hv.y));
            t[3] = (short)f2bf(z0.w + hi16f(hv.y));
            t[4] = (short)f2bf(z1.x + lo16f(hv.z));
            t[5] = (short)f2bf(z1.y + hi16f(hv.z));
            t[6] = (short)f2bf(z1.z + lo16f(hv.w));
            t[7] = (short)f2bf(z1.w + hi16f(hv.w));
            a[sub][kk] = t;
        }
    }

    f32x4 acc[2][8];
    #pragma unroll
    for (int s2 = 0; s2 < 2; ++s2)
        #pragma unroll
        for (int t = 0; t < 8; ++t)
            acc[s2][t] = (f32x4){0.f, 0.f, 0.f, 0.f};

    __syncthreads();

    #pragma unroll
    for (int t = 0; t < 8; ++t) {
        const unsigned short* wrow = W1t + (size_t)(t * 16 + m) * D;
        bf16x8 bfr[4];
        #pragma unroll
        for (int k = 0; k < 4; ++k)
            bfr[k] = __builtin_bit_cast(bf16x8, *(const uint4*)&wrow[k * 32 + q * 8]);
        #pragma unroll
        for (int sub = 0; sub < 2; ++sub) {
            acc[sub][t] = __builtin_amdgcn_mfma_f32_16x16x32_bf16(a[sub][0], bfr[0], acc[sub][t], 0, 0, 0);
            acc[sub][t] = __builtin_amdgcn_mfma_f32_16x16x32_bf16(a[sub][1], bfr[1], acc[sub][t], 0, 0, 0);
            acc[sub][t] = __builtin_amdgcn_mfma_f32_16x16x32_bf16(a[sub][2], bfr[2], acc[sub][t], 0, 0, 0);
            acc[sub][t] = __builtin_amdgcn_mfma_f32_16x16x32_bf16(a[sub][3], bfr[3], acc[sub][t], 0, 0, 0);
        }
    }

    // re-zero zin for next layer (loads above consumed by GEMM1; stores
    // overlap epilogue + GEMM2).  Only the thread that owns the row writes.
    if (zero_self) {
        const float4 z4 = make_float4(0.f, 0.f, 0.f, 0.f);
        #pragma unroll
        for (int sub = 0; sub < 2; ++sub) {
            if (!live[sub]) continue;
            int node = node0 + wv * 32 + sub * 16 + m;
            float* zr = zin_f + (size_t)node * D;
            #pragma unroll
            for (int kk = 0; kk < 4; ++kk) {
                *(float4*)(zr + kk * 32 + q * 8)     = z4;
                *(float4*)(zr + kk * 32 + q * 8 + 4) = z4;
            }
        }
    }

    #pragma unroll
    for (int sub = 0; sub < 2; ++sub)
        #pragma unroll
        for (int t = 0; t < 8; ++t) {
            int col = t * 16 + m;
            float sc = scale_s[col], sh = shift_s[col];
            #pragma unroll
            for (int rr = 0; rr < 4; ++rr) {
                float v = fmaxf(acc[sub][t][rr] * sc + sh, 0.f);
                int row = wv * 32 + sub * 16 + q * 4 + rr;
                zmid[row * 136 + col] = f2bf(v);
            }
        }

    __syncthreads();

    bf16x8 a2[2][4];
    #pragma unroll
    for (int sub = 0; sub < 2; ++sub) {
        const unsigned short* zr = &zmid[(wv * 32 + sub * 16 + m) * 136];
        #pragma unroll
        for (int k = 0; k < 4; ++k)
            a2[sub][k] = __builtin_bit_cast(bf16x8, *(const uint4*)&zr[k * 32 + q * 8]);
    }

    #pragma unroll
    for (int s2 = 0; s2 < 2; ++s2)
        #pragma unroll
        for (int t = 0; t < 8; ++t)
            acc[s2][t] = (f32x4){0.f, 0.f, 0.f, 0.f};

    #pragma unroll
    for (int t = 0; t < 8; ++t) {
        const unsigned short* wrow = W2t + (size_t)(t * 16 + m) * D;
        bf16x8 bfr[4];
        #pragma unroll
        for (int k = 0; k < 4; ++k)
            bfr[k] = __builtin_bit_cast(bf16x8, *(const uint4*)&wrow[k * 32 + q * 8]);
        #pragma unroll
        for (int sub = 0; sub < 2; ++sub) {
            acc[sub][t] = __builtin_amdgcn_mfma_f32_16x16x32_bf16(a2[sub][0], bfr[0], acc[sub][t], 0, 0, 0);
            acc[sub][t] = __builtin_amdgcn_mfma_f32_16x16x32_bf16(a2[sub][1], bfr[1], acc[sub][t], 0, 0, 0);
            acc[sub][t] = __builtin_amdgcn_mfma_f32_16x16x32_bf16(a2[sub][2], bfr[2], acc[sub][t], 0, 0, 0);
            acc[sub][t] = __builtin_amdgcn_mfma_f32_16x16x32_bf16(a2[sub][3], bfr[3], acc[sub][t], 0, 0, 0);
        }
    }

    #pragma unroll
    for (int sub = 0; sub < 2; ++sub)
        #pragma unroll
        for (int rr = 0; rr < 4; ++rr) {
            int node = node0 + wv * 32 + sub * 16 + q * 4 + rr;
            if (node < N_NODES) {
                unsigned short* hrow = hout_b + (size_t)node * D;
                #pragma unroll
                for (int t = 0; t < 8; ++t) {
                    int col = t * 16 + m;
                    hrow[col] = f2bf(fmaxf(acc[sub][t][rr] + b2_s[col], 0.f));
                }
            }
        }
}

// ---------------------------------------------------------------------------
// Pool v2: segmented sum over sorted batch (bf16 in, fp32 out).
// u32 loads (2 feats/thread), 8-way row split + LDS combine. No atomics.
// ---------------------------------------------------------------------------
__global__ __launch_bounds__(512) void pool_kernel(
    const unsigned short* __restrict__ hout_b, const int* __restrict__ goff,
    float* __restrict__ pool, int layer_off)
{
    __shared__ float2 part[7][64];
    const int g   = blockIdx.x;
    const int j2  = threadIdx.x & 63;      // owns feats 2*j2, 2*j2+1
    const int grp = threadIdx.x >> 6;      // 0..7
    const int beg = goff[g], end = goff[g + 1];
    const int len = end - beg;
    const int ch  = (len + 7) >> 3;
    int lo = beg + grp * ch;
    int hi = lo + ch;
    if (hi > end) hi = end;
    float ax = 0.f, ay = 0.f;
    for (int r = lo; r < hi; ++r) {
        const u32 v = *(const u32*)(hout_b + (size_t)r * D + 2 * j2);
        ax += lo16f(v);
        ay += hi16f(v);
    }
    if (grp) part[grp - 1][j2] = make_float2(ax, ay);
    __syncthreads();
    if (grp == 0) {
        #pragma unroll
        for (int i = 0; i < 7; ++i) {
            float2 p = part[i][j2];
            ax += p.x; ay += p.y;
        }
        *(float2*)(pool + g * (LAYERS * D) + layer_off + 2 * j2) =
            make_float2(ax, ay);
    }
}

// ---------------------------------------------------------------------------
// Head: out[g] = relu(pool[g] @ lin1_W + lin1_b) @ lin2_W + lin2_b
// ---------------------------------------------------------------------------
__global__ __launch_bounds__(384) void head_kernel(
    const float* __restrict__ pool,
    const float* __restrict__ lin1W,
    const float* __restrict__ lin1b,
    const float* __restrict__ lin2W,
    const float* __restrict__ lin2b,
    float*       __restrict__ out)
{
    __shared__ float gs[LAYERS * D];
    __shared__ float red[LAYERS * D];
    const int g   = blockIdx.x;
    const int tid = threadIdx.x;
    gs[tid] = pool[g * (LAYERS * D) + tid];
    __syncthreads();

    float acc = lin1b[tid];
    #pragma unroll 4
    for (int k = 0; k < LAYERS * D; ++k)
        acc = fmaf(gs[k], lin1W[k * (LAYERS * D) + tid], acc);
    acc = fmaxf(acc, 0.0f);
    float p = acc * lin2W[tid];

    red[tid] = p;
    __syncthreads();
    if (tid < 128) red[tid] = red[tid] + red[tid + 128] + red[tid + 256];
    __syncthreads();
    if (tid < 64) {
        float v = red[tid] + red[tid + 64];
        v += __shfl_down(v, 32);
        v += __shfl_down(v, 16);
        v += __shfl_down(v, 8);
        v += __shfl_down(v, 4);
        v += __shfl_down(v, 2);
        v += __shfl_down(v, 1);
        if (tid == 0) out[g] = v + lin2b[0];
    }
}

// ---------------------------------------------------------------------------
extern "C" void kernel_launch(void* const* d_in, const int* in_sizes, int n_in,
                              void* d_out, int out_size, void* d_ws, size_t ws_size,
                              hipStream_t stream)
{
    const float* x         = (const float*)d_in[0];
    const float* edge_attr = (const float*)d_in[1];
    const float* elW       = (const float*)d_in[2];
    const float* elb       = (const float*)d_in[3];
    const float* W1        = (const float*)d_in[4];
    const float* b1        = (const float*)d_in[5];
    const float* bn_g      = (const float*)d_in[6];
    const float* bn_b      = (const float*)d_in[7];
    const float* bn_mean   = (const float*)d_in[8];
    const float* bn_var    = (const float*)d_in[9];
    const float* W2        = (const float*)d_in[10];
    const float* b2        = (const float*)d_in[11];
    const float* lin1W     = (const float*)d_in[12];
    const float* lin1b     = (const float*)d_in[13];
    const float* lin2W     = (const float*)d_in[14];
    const float* lin2b     = (const float*)d_in[15];
    const int*   ei        = (const int*)d_in[16];
    const int*   batch     = (const int*)d_in[17];
    const int*   src = ei;
    const int*   dst = ei + N_EDGES;

    // Workspace layout, all 16B-aligned:
    float*          pool       = (float*)d_ws;                              // G*384 f32
    unsigned short* xb         = (unsigned short*)(pool + (size_t)N_GRAPHS * LAYERS * D);
    unsigned short* hA_b       = xb   + (size_t)N_NODES * D;                // bf16
    float*          zin_f      = (float*)(hA_b + (size_t)N_NODES * D);      // [N][128] f32
    unsigned short* Wt         = (unsigned short*)(zin_f + (size_t)N_NODES * D);
    uint4*          elWf       = (uint4*)(Wt + 6 * D * D);                  // 3*8*64 uint4
    u32*            sorted_eah = (u32*)(elWf + LAYERS * 8 * 64);            // E*8 u32
    int*            srcdst     = (int*)(sorted_eah + (size_t)N_EDGES * 8);  // E int2
    int*            counts     = srcdst + (size_t)N_EDGES * 2;
    int*            offsets    = counts + N_NODES;                          // N+1
    int*            cursor     = offsets + N_NODES + 4;
    int*            goff       = cursor + N_NODES + 4;                      // 513 ints
    int*            blocksum   = goff + N_GRAPHS + 4;
    int*            blockbase  = blocksum + SCAN_NB + 4;

    hipMemsetAsync(counts, 0, (size_t)N_NODES * sizeof(int), stream);
    hipMemsetAsync(zin_f, 0, (size_t)N_NODES * D * sizeof(float), stream);

    // --- once-per-call prep ---
    wprep_kernel<<<6, 256, 0, stream>>>(W1, W2, Wt);
    elprep_kernel<<<LAYERS, 512, 0, stream>>>(elW, elb, elWf);
    xprep_kernel<<<(N_NODES * D) / 256, 256, 0, stream>>>(x, xb);
    goff_kernel<<<1, 512, 0, stream>>>(batch, goff);
    hist_kernel<<<N_EDGES / 256, 256, 0, stream>>>(dst, counts);
    scan1_kernel<<<SCAN_NB, 256, 0, stream>>>(counts, blocksum);
    scan2_kernel<<<1, 256, 0, stream>>>(blocksum, blockbase);
    scan3_kernel<<<SCAN_NB, 256, 0, stream>>>(counts, blockbase, offsets, cursor);
    scatter_kernel<<<N_EDGES / 256, 256, 0, stream>>>(
        src, dst, edge_attr, cursor, (int2*)srcdst, (uint4*)sorted_eah);

    const unsigned short* hin_b = xb;
    for (int l = 0; l < LAYERS; ++l) {
        aggr_kernel<<<AGGR_BLK, 128, 0, stream>>>(
            hin_b, (const uint4*)sorted_eah, srcdst,
            elWf + (size_t)l * 8 * 64, zin_f);
        node_mlp<<<(N_NODES + 63) / 64, 128, 0, stream>>>(
            zin_f, hin_b,
            Wt + (size_t)(l * 2)     * D * D, b1 + l * D,
            bn_g + l * D, bn_b + l * D, bn_mean + l * D, bn_var + l * D,
            Wt + (size_t)(l * 2 + 1) * D * D, b2 + l * D,
            hA_b, (l < LAYERS - 1) ? 1 : 0);
        pool_kernel<<<N_GRAPHS, 512, 0, stream>>>(hA_b, goff, pool, l * D);
        hin_b = hA_b;
    }

    head_kernel<<<N_GRAPHS, LAYERS * D, 0, stream>>>(
        pool, lin1W, lin1b, lin2W, lin2b, (float*)d_out);
}

// Round 9
// 715.603 us; speedup vs baseline: 1.1624x; 1.0747x over previous
//
#include <hip/hip_runtime.h>

#define N_NODES   50000
#define N_EDGES   1600000
#define N_GRAPHS  512
#define LAYERS    3
#define D         128
#define EF        16
#define BN_EPS    1e-5f

#define SCAN_CH   256
#define SCAN_NB   ((N_NODES + SCAN_CH - 1) / SCAN_CH)   // 196

#define NCHUNK    (N_EDGES / 16)        // 100000 (E % 16 == 0)
#define AGGR_BLK  2048
#define AGGR_WPB  2
#define NWAVES    (AGGR_BLK * AGGR_WPB) // 4096
#define FSTR      20                    // dwords/feat-row: 16B-aligned, 2-way banks

typedef unsigned int u32;
typedef short bf16x8 __attribute__((ext_vector_type(8)));
typedef float f32x4 __attribute__((ext_vector_type(4)));

__device__ __forceinline__ unsigned short f2bf(float f) {   // RNE f32->bf16
    unsigned u = __builtin_bit_cast(unsigned, f);
    u += 0x7FFF + ((u >> 16) & 1);
    return (unsigned short)(u >> 16);
}

__device__ __forceinline__ float bf2f(unsigned short u) {
    return __builtin_bit_cast(float, (unsigned)u << 16);
}

__device__ __forceinline__ float lo16f(u32 u) {
    return __builtin_bit_cast(float, u << 16);
}
__device__ __forceinline__ float hi16f(u32 u) {
    return __builtin_bit_cast(float, u & 0xFFFF0000u);
}

__device__ __forceinline__ u32 pack_bf2(float x, float y) {
    return ((u32)f2bf(x)) | ((u32)f2bf(y) << 16);
}

// ---------------------------------------------------------------------------
// CSR build step 1: histogram of dst (counts pre-zeroed).
// ---------------------------------------------------------------------------
__global__ __launch_bounds__(256) void hist_kernel(
    const int* __restrict__ dst, int* __restrict__ counts)
{
    int e = blockIdx.x * 256 + threadIdx.x;
    atomicAdd(&counts[dst[e]], 1);
}

// ---------------------------------------------------------------------------
// Hierarchical scan, 3 phases.
// ---------------------------------------------------------------------------
__global__ __launch_bounds__(256) void scan1_kernel(
    const int* __restrict__ counts, int* __restrict__ blocksum)
{
    const int t = threadIdx.x;
    const int i = blockIdx.x * SCAN_CH + t;
    int v = (i < N_NODES) ? counts[i] : 0;
    #pragma unroll
    for (int off = 32; off > 0; off >>= 1)
        v += __shfl_down(v, off);
    __shared__ int ws[4];
    if ((t & 63) == 0) ws[t >> 6] = v;
    __syncthreads();
    if (t == 0) blocksum[blockIdx.x] = ws[0] + ws[1] + ws[2] + ws[3];
}

__global__ __launch_bounds__(256) void scan2_kernel(
    const int* __restrict__ blocksum, int* __restrict__ blockbase)
{
    __shared__ int s[256];
    const int t = threadIdx.x;
    int v = (t < SCAN_NB) ? blocksum[t] : 0;
    s[t] = v;
    __syncthreads();
    for (int off = 1; off < 256; off <<= 1) {
        int u = (t >= off) ? s[t - off] : 0;
        __syncthreads();
        s[t] += u;
        __syncthreads();
    }
    if (t < SCAN_NB) blockbase[t] = s[t] - v;
}

__global__ __launch_bounds__(256) void scan3_kernel(
    const int* __restrict__ counts, const int* __restrict__ blockbase,
    int* __restrict__ offsets, int* __restrict__ cursor)
{
    __shared__ int s[256];
    const int t = threadIdx.x;
    const int i = blockIdx.x * SCAN_CH + t;
    int v = (i < N_NODES) ? counts[i] : 0;
    s[t] = v;
    __syncthreads();
    for (int off = 1; off < 256; off <<= 1) {
        int u = (t >= off) ? s[t - off] : 0;
        __syncthreads();
        s[t] += u;
        __syncthreads();
    }
    if (i < N_NODES) {
        const int base = blockbase[blockIdx.x];
        const int excl = base + s[t] - v;
        offsets[i] = excl;
        cursor[i]  = excl;
        if (i == N_NODES - 1) offsets[N_NODES] = base + s[t];
    }
}

// ---------------------------------------------------------------------------
// Scatter v3: 1 edge/thread for max TLP (R6 lesson: intra-thread ILP
// serializes; latency is hidden by wave count).  Writes per edge:
// 2 x uint4 ea (bf16) + 1 x int2 {src,dst}.
// ---------------------------------------------------------------------------
__global__ __launch_bounds__(256) void scatter_kernel(
    const int* __restrict__ src, const int* __restrict__ dst,
    const float* __restrict__ edge_attr,
    int* __restrict__ cursor, int2* __restrict__ srcdst,
    uint4* __restrict__ sorted_eah)
{
    int e = blockIdx.x * 256 + threadIdx.x;
    int d = dst[e];
    int pos = atomicAdd(&cursor[d], 1);
    srcdst[pos] = make_int2(src[e], d);
    const float4* ea = (const float4*)(edge_attr + (size_t)e * EF);
    float4 a0 = ea[0], a1 = ea[1], a2 = ea[2], a3 = ea[3];
    uint4 o0, o1;
    o0.x = pack_bf2(a0.x, a0.y); o0.y = pack_bf2(a0.z, a0.w);
    o0.z = pack_bf2(a1.x, a1.y); o0.w = pack_bf2(a1.z, a1.w);
    o1.x = pack_bf2(a2.x, a2.y); o1.y = pack_bf2(a2.z, a2.w);
    o1.z = pack_bf2(a3.x, a3.y); o1.w = pack_bf2(a3.z, a3.w);
    sorted_eah[(size_t)pos * 2]     = o0;
    sorted_eah[(size_t)pos * 2 + 1] = o1;
}

// ---------------------------------------------------------------------------
// Graph offsets: batch is sorted; goff[g] = lower_bound(batch, g), goff[512]=N.
// ---------------------------------------------------------------------------
__global__ __launch_bounds__(512) void goff_kernel(
    const int* __restrict__ batch, int* __restrict__ goff)
{
    const int g = threadIdx.x;
    int lo = 0, hi = N_NODES;
    while (lo < hi) {
        int mid = (lo + hi) >> 1;
        if (batch[mid] < g) lo = mid + 1; else hi = mid;
    }
    goff[g] = lo;
    if (g == 0) goff[N_GRAPHS] = N_NODES;
}

// ---------------------------------------------------------------------------
// Weight prep: transpose W1/W2 (all layers) to bf16 Wt[out][k], once per call.
// ---------------------------------------------------------------------------
__global__ __launch_bounds__(256) void wprep_kernel(
    const float* __restrict__ W1, const float* __restrict__ W2,
    unsigned short* __restrict__ Wt)
{
    const int matid = blockIdx.x;          // l*2 + (0:W1, 1:W2)
    const int l = matid >> 1;
    const float* srcm = (matid & 1) ? (W2 + (size_t)l * D * D)
                                    : (W1 + (size_t)l * D * D);
    unsigned short* out = Wt + (size_t)matid * D * D;
    for (int i = 0; i < 64; ++i) {
        int idx = threadIdx.x + i * 256;
        int k = idx >> 7, n = idx & 127;
        out[n * D + k] = f2bf(srcm[idx]);
    }
}

// ---------------------------------------------------------------------------
// elW B-fragment prep (verified): per layer, 8 tiles x 64 lanes x 8 bf16.
// k 0..15 = elW; k16 = elb (bias trick); k17..31 = 0.
// ---------------------------------------------------------------------------
__global__ __launch_bounds__(512) void elprep_kernel(
    const float* __restrict__ elW, const float* __restrict__ elb,
    uint4* __restrict__ elWf)                 // [LAYERS][8][64]
{
    const int l    = blockIdx.x;
    const int t    = threadIdx.x >> 6;
    const int lane = threadIdx.x & 63;
    const int q = lane >> 4, c = lane & 15;
    const float* W = elW + (size_t)l * EF * D;
    unsigned short h[8];
    #pragma unroll
    for (int i = 0; i < 8; ++i) {
        int k = q * 8 + i;
        float v = 0.f;
        if (q < 2)                 v = W[k * D + t * 16 + c];
        else if (q == 2 && i == 0) v = elb[l * D + t * 16 + c];
        h[i] = f2bf(v);
    }
    uint4 o;
    o.x = (u32)h[0] | ((u32)h[1] << 16);
    o.y = (u32)h[2] | ((u32)h[3] << 16);
    o.z = (u32)h[4] | ((u32)h[5] << 16);
    o.w = (u32)h[6] | ((u32)h[7] << 16);
    elWf[((size_t)l * 8 + t) * 64 + lane] = o;
}

// ---------------------------------------------------------------------------
// x -> bf16 (once per call).
// ---------------------------------------------------------------------------
__global__ __launch_bounds__(256) void xprep_kernel(
    const float* __restrict__ x, unsigned short* __restrict__ xb)
{
    int i = blockIdx.x * 256 + threadIdx.x;
    xb[i] = f2bf(x[i]);
}

// ---------------------------------------------------------------------------
// Per-layer aggregation v7 (feat-major LDS, b128 both sides):
//   zin_f[n][:] += sum_{e: dst=n} relu(h[src_e] + ea_e@elW + elb)
// Per 16-edge chunk the LDS traffic is 8 ds_write_b128 (one per MFMA tile:
// lane's C frag = 4 consecutive edges of one feature) + 8 ds_read_b128
// (lane reads its 2 feature rows x 4 edge-blocks) = 16 LDS instr vs 64 in
// v6.  Layout: e_lds[feat][FSTR=20 dwords], edge-block position XOR-swizzled
// by (feat>>3)&3 -> 2-way banks everywhere (free).  Interior-run flushes are
// plain stores (only first/last run of a wave can be shared -> atomic).
// ---------------------------------------------------------------------------
__global__ __launch_bounds__(128) void aggr_kernel(
    const unsigned short* __restrict__ h_b,    // [N][128] bf16
    const uint4* __restrict__ sorted_ea,       // [E] 2 x uint4 (bf16x16)
    const int*   __restrict__ srcdst,          // [E] packed {src,dst}, dst nondecr.
    const uint4* __restrict__ elWf,            // [8][64] this layer
    float* __restrict__ zin_f)                 // [N][128] f32, pre-zeroed
{
    __shared__ float e_lds_all[AGGR_WPB][128 * FSTR];   // 2 x 10 KB
    const int tid  = threadIdx.x;
    const int wv   = __builtin_amdgcn_readfirstlane(tid >> 6);
    const int lane = tid & 63;
    const int q    = lane >> 4;
    const int c    = lane & 15;
    const int w    = blockIdx.x * AGGR_WPB + wv;

    float* e_lds = e_lds_all[wv];

    // B fragments (verified layout), L2-resident
    bf16x8 bfr[8];
    #pragma unroll
    for (int t = 0; t < 8; ++t)
        bfr[t] = __builtin_bit_cast(bf16x8, elWf[t * 64 + lane]);

    // A-frag masks: q<2 pass ea; q2 -> k16 = bf16(1.0) bias row; q3 -> 0
    const u32 mand = (q < 2) ? 0xFFFFFFFFu : 0u;
    const u32 mor0 = (q == 2) ? 0x3F80u : 0u;

    const int qc = NCHUNK / NWAVES, rc = NCHUNK % NWAVES;
    const int c0 = w * qc + (w < rc ? w : rc);
    const int cn = qc + (w < rc ? 1 : 0);
    const int e_lo = c0 * 16;
    const int e_hi = (c0 + cn) * 16;

    int cur = srcdst[(size_t)e_lo * 2 + 1];   // first dst, wave-uniform
    bool first_flush = true;                  // first node may be shared w/ prev wave
    float accA = 0.f, accB = 0.f;
    const f32x4 zero4 = (f32x4){0.f, 0.f, 0.f, 0.f};
    const int sA = (lane >> 3) & 3;           // read-side swizzle (same for row+64)

#define HLOAD(I, SV)                                                          \
    const u32 hA##I = h_b[(size_t)(SV) * D + lane];                           \
    const u32 hB##I = h_b[(size_t)(SV) * D + 64 + lane];

#define FLUSH(ATOM)                                                           \
    {                                                                         \
        if (ATOM) {                                                           \
            atomicAdd(&zin_f[(size_t)cur * D + lane],      accA);             \
            atomicAdd(&zin_f[(size_t)cur * D + 64 + lane], accB);             \
        } else {                                                              \
            zin_f[(size_t)cur * D + lane]      = accA;                        \
            zin_f[(size_t)cur * D + 64 + lane] = accB;                        \
        }                                                                     \
    }

#define ACC(I, DV)                                                            \
    {                                                                         \
        if ((DV) != cur) {                                                    \
            FLUSH(first_flush);                                               \
            first_flush = false;                                              \
            accA = 0.f; accB = 0.f; cur = (DV);                               \
        }                                                                     \
        accA += fmaxf(vA[(I) >> 2][(I) & 3] + bf2f((unsigned short)hA##I), 0.f); \
        accB += fmaxf(vB[(I) >> 2][(I) & 3] + bf2f((unsigned short)hB##I), 0.f); \
    }

    for (int e0 = e_lo; e0 < e_hi; e0 += 16) {
        // --- wave-uniform packed ids: 8 x int4 = (s,d,s,d) ---
        const int4* sp = (const int4*)(srcdst + (size_t)e0 * 2);
        const int4 p0 = sp[0], p1 = sp[1], p2 = sp[2], p3 = sp[3];
        const int4 p4 = sp[4], p5 = sp[5], p6 = sp[6], p7 = sp[7];

        // --- issue all 32 coalesced h gathers (latency hides under MFMA) ---
        HLOAD(0,  p0.x) HLOAD(1,  p0.z) HLOAD(2,  p1.x) HLOAD(3,  p1.z)
        HLOAD(4,  p2.x) HLOAD(5,  p2.z) HLOAD(6,  p3.x) HLOAD(7,  p3.z)
        HLOAD(8,  p4.x) HLOAD(9,  p4.z) HLOAD(10, p5.x) HLOAD(11, p5.z)
        HLOAD(12, p6.x) HLOAD(13, p6.z) HLOAD(14, p7.x) HLOAD(15, p7.z)

        // --- phase 1: E = ea@elW + elb -> LDS feat-major, one b128/tile ---
        uint4 araw = sorted_ea[(size_t)(e0 + c) * 2 + (q & 1)];
        uint4 aw;
        aw.x = (araw.x & mand) | mor0;
        aw.y =  araw.y & mand;
        aw.z =  araw.z & mand;
        aw.w =  araw.w & mand;
        const bf16x8 afr = __builtin_bit_cast(bf16x8, aw);

        #pragma unroll
        for (int t = 0; t < 8; ++t) {
            f32x4 C = __builtin_amdgcn_mfma_f32_16x16x32_bf16(
                afr, bfr[t], zero4, 0, 0, 0);
            // C[rr] = E[edge 4q+rr][feat 16t+c]: 4 consecutive edges, one feat
            const int f = t * 16 + c;
            const int s = (2 * t + (c >> 3)) & 3;          // (f>>3)&3
            *(float4*)&e_lds[f * FSTR + ((q ^ s) << 2)] =
                make_float4(C[0], C[1], C[2], C[3]);       // ds_write_b128
        }

        // --- read back this lane's 2 feature rows, 4 edge-blocks each ---
        f32x4 vA[4], vB[4];
        #pragma unroll
        for (int b = 0; b < 4; ++b) {
            vA[b] = *(const f32x4*)&e_lds[lane * FSTR + ((b ^ sA) << 2)];
            vB[b] = *(const f32x4*)&e_lds[(64 + lane) * FSTR + ((b ^ sA) << 2)];
        }

        // --- register-only serial segmented accumulate ---
        ACC(0,  p0.y) ACC(1,  p0.w) ACC(2,  p1.y) ACC(3,  p1.w)
        ACC(4,  p2.y) ACC(5,  p2.w) ACC(6,  p3.y) ACC(7,  p3.w)
        ACC(8,  p4.y) ACC(9,  p4.w) ACC(10, p5.y) ACC(11, p5.w)
        ACC(12, p6.y) ACC(13, p6.w) ACC(14, p7.y) ACC(15, p7.w)
    }
#undef HLOAD
#undef ACC

    FLUSH(true);    // last node may be shared with the next wave
#undef FLUSH
}

// ---------------------------------------------------------------------------
// Fused node MLP via MFMA (bf16 in, fp32 accumulate):
//   hout_b = bf16(relu(relu(BN((h+zin_f)@W1+b1))@W2 + b2))
// +h and f32->bf16 folded into the A-frag load.  If zero_self, each thread
// re-zeroes EXACTLY the zin addresses it loaded (placed after GEMM1, so the
// loads are provably consumed) -> replaces the per-layer zin memset.
// ---------------------------------------------------------------------------
__global__ __launch_bounds__(128) void node_mlp(
    float* __restrict__ zin_f,                  // [N][128] f32 (aggr sums)
    const unsigned short* __restrict__ h_in,    // [N][128] bf16 (layer input)
    const unsigned short* __restrict__ W1t,     // [128 out][128 k] bf16
    const float* __restrict__ b1,
    const float* __restrict__ bng, const float* __restrict__ bnb,
    const float* __restrict__ bnm, const float* __restrict__ bnv,
    const unsigned short* __restrict__ W2t,
    const float* __restrict__ b2,
    unsigned short* __restrict__ hout_b,
    const int zero_self)
{
    __shared__ unsigned short zmid[64 * 136];   // 17.4 KB
    __shared__ float scale_s[128], shift_s[128], b2_s[128];

    const int tid  = threadIdx.x;
    const int wv   = tid >> 6;
    const int lane = tid & 63;
    const int q    = lane >> 4;
    const int m    = lane & 15;
    const int node0 = blockIdx.x * 64;

    {
        float sc = bng[tid] * rsqrtf(bnv[tid] + BN_EPS);
        scale_s[tid] = sc;
        shift_s[tid] = b1[tid] * sc + bnb[tid] - bnm[tid] * sc;
        b2_s[tid]    = b2[tid];
    }

    // A fragments: bf16(h + zin_f)
    bf16x8 a[2][4];
    bool live[2];
    #pragma unroll
    for (int sub = 0; sub < 2; ++sub) {
        int node = node0 + wv * 32 + sub * 16 + m;
        live[sub] = node < N_NODES;
        if (!live[sub]) node = N_NODES - 1;
        const float* zr = zin_f + (size_t)node * D;
        const unsigned short* hr = h_in + (size_t)node * D;
        #pragma unroll
        for (int kk = 0; kk < 4; ++kk) {
            const int base = kk * 32 + q * 8;
            float4 z0 = *(const float4*)(zr + base);
            float4 z1 = *(const float4*)(zr + base + 4);
            uint4  hv = *(const uint4*)(hr + base);
            bf16x8 t;
            t[0] = (short)f2bf(z0.x + lo16f(hv.x));
            t[1] = (short)f2bf(z0.y + hi16f(hv.x));
            t[2] = (short)f2bf(z0.z + lo16f(hv.y));
            t[3] = (short)f2bf(z0.w + hi16f(hv.y));
            t[4] = (short)f2bf(z1.x + lo16f(hv.z));
            t[5] = (short)f2bf(z1.y + hi16f(hv.z));
            t[6] = (short)f2bf(z1.z + lo16f(hv.w));
            t[7] = (short)f2bf(z1.w + hi16f(hv.w));
            a[sub][kk] = t;
        }
    }

    f32x4 acc[2][8];
    #pragma unroll
    for (int s2 = 0; s2 < 2; ++s2)
        #pragma unroll
        for (int t = 0; t < 8; ++t)
            acc[s2][t] = (f32x4){0.f, 0.f, 0.f, 0.f};

    __syncthreads();

    #pragma unroll
    for (int t = 0; t < 8; ++t) {
        const unsigned short* wrow = W1t + (size_t)(t * 16 + m) * D;
        bf16x8 bfr[4];
        #pragma unroll
        for (int k = 0; k < 4; ++k)
            bfr[k] = __builtin_bit_cast(bf16x8, *(const uint4*)&wrow[k * 32 + q * 8]);
        #pragma unroll
        for (int sub = 0; sub < 2; ++sub) {
            acc[sub][t] = __builtin_amdgcn_mfma_f32_16x16x32_bf16(a[sub][0], bfr[0], acc[sub][t], 0, 0, 0);
            acc[sub][t] = __builtin_amdgcn_mfma_f32_16x16x32_bf16(a[sub][1], bfr[1], acc[sub][t], 0, 0, 0);
            acc[sub][t] = __builtin_amdgcn_mfma_f32_16x16x32_bf16(a[sub][2], bfr[2], acc[sub][t], 0, 0, 0);
            acc[sub][t] = __builtin_amdgcn_mfma_f32_16x16x32_bf16(a[sub][3], bfr[3], acc[sub][t], 0, 0, 0);
        }
    }

    // re-zero zin for next layer (loads above consumed by GEMM1; stores
    // overlap epilogue + GEMM2).  Only the thread that owns the row writes.
    if (zero_self) {
        const float4 z4 = make_float4(0.f, 0.f, 0.f, 0.f);
        #pragma unroll
        for (int sub = 0; sub < 2; ++sub) {
            if (!live[sub]) continue;
            int node = node0 + wv * 32 + sub * 16 + m;
            float* zr = zin_f + (size_t)node * D;
            #pragma unroll
            for (int kk = 0; kk < 4; ++kk) {
                *(float4*)(zr + kk * 32 + q * 8)     = z4;
                *(float4*)(zr + kk * 32 + q * 8 + 4) = z4;
            }
        }
    }

    #pragma unroll
    for (int sub = 0; sub < 2; ++sub)
        #pragma unroll
        for (int t = 0; t < 8; ++t) {
            int col = t * 16 + m;
            float sc = scale_s[col], sh = shift_s[col];
            #pragma unroll
            for (int rr = 0; rr < 4; ++rr) {
                float v = fmaxf(acc[sub][t][rr] * sc + sh, 0.f);
                int row = wv * 32 + sub * 16 + q * 4 + rr;
                zmid[row * 136 + col] = f2bf(v);
            }
        }

    __syncthreads();

    bf16x8 a2[2][4];
    #pragma unroll
    for (int sub = 0; sub < 2; ++sub) {
        const unsigned short* zr = &zmid[(wv * 32 + sub * 16 + m) * 136];
        #pragma unroll
        for (int k = 0; k < 4; ++k)
            a2[sub][k] = __builtin_bit_cast(bf16x8, *(const uint4*)&zr[k * 32 + q * 8]);
    }

    #pragma unroll
    for (int s2 = 0; s2 < 2; ++s2)
        #pragma unroll
        for (int t = 0; t < 8; ++t)
            acc[s2][t] = (f32x4){0.f, 0.f, 0.f, 0.f};

    #pragma unroll
    for (int t = 0; t < 8; ++t) {
        const unsigned short* wrow = W2t + (size_t)(t * 16 + m) * D;
        bf16x8 bfr[4];
        #pragma unroll
        for (int k = 0; k < 4; ++k)
            bfr[k] = __builtin_bit_cast(bf16x8, *(const uint4*)&wrow[k * 32 + q * 8]);
        #pragma unroll
        for (int sub = 0; sub < 2; ++sub) {
            acc[sub][t] = __builtin_amdgcn_mfma_f32_16x16x32_bf16(a2[sub][0], bfr[0], acc[sub][t], 0, 0, 0);
            acc[sub][t] = __builtin_amdgcn_mfma_f32_16x16x32_bf16(a2[sub][1], bfr[1], acc[sub][t], 0, 0, 0);
            acc[sub][t] = __builtin_amdgcn_mfma_f32_16x16x32_bf16(a2[sub][2], bfr[2], acc[sub][t], 0, 0, 0);
            acc[sub][t] = __builtin_amdgcn_mfma_f32_16x16x32_bf16(a2[sub][3], bfr[3], acc[sub][t], 0, 0, 0);
        }
    }

    #pragma unroll
    for (int sub = 0; sub < 2; ++sub)
        #pragma unroll
        for (int rr = 0; rr < 4; ++rr) {
            int node = node0 + wv * 32 + sub * 16 + q * 4 + rr;
            if (node < N_NODES) {
                unsigned short* hrow = hout_b + (size_t)node * D;
                #pragma unroll
                for (int t = 0; t < 8; ++t) {
                    int col = t * 16 + m;
                    hrow[col] = f2bf(fmaxf(acc[sub][t][rr] + b2_s[col], 0.f));
                }
            }
        }
}

// ---------------------------------------------------------------------------
// Pool v2: segmented sum over sorted batch (bf16 in, fp32 out).
// u32 loads (2 feats/thread), 8-way row split + LDS combine. No atomics.
// ---------------------------------------------------------------------------
__global__ __launch_bounds__(512) void pool_kernel(
    const unsigned short* __restrict__ hout_b, const int* __restrict__ goff,
    float* __restrict__ pool, int layer_off)
{
    __shared__ float2 part[7][64];
    const int g   = blockIdx.x;
    const int j2  = threadIdx.x & 63;      // owns feats 2*j2, 2*j2+1
    const int grp = threadIdx.x >> 6;      // 0..7
    const int beg = goff[g], end = goff[g + 1];
    const int len = end - beg;
    const int ch  = (len + 7) >> 3;
    int lo = beg + grp * ch;
    int hi = lo + ch;
    if (hi > end) hi = end;
    float ax = 0.f, ay = 0.f;
    for (int r = lo; r < hi; ++r) {
        const u32 v = *(const u32*)(hout_b + (size_t)r * D + 2 * j2);
        ax += lo16f(v);
        ay += hi16f(v);
    }
    if (grp) part[grp - 1][j2] = make_float2(ax, ay);
    __syncthreads();
    if (grp == 0) {
        #pragma unroll
        for (int i = 0; i < 7; ++i) {
            float2 p = part[i][j2];
            ax += p.x; ay += p.y;
        }
        *(float2*)(pool + g * (LAYERS * D) + layer_off + 2 * j2) =
            make_float2(ax, ay);
    }
}

// ---------------------------------------------------------------------------
// Head: out[g] = relu(pool[g] @ lin1_W + lin1_b) @ lin2_W + lin2_b
// ---------------------------------------------------------------------------
__global__ __launch_bounds__(384) void head_kernel(
    const float* __restrict__ pool,
    const float* __restrict__ lin1W,
    const float* __restrict__ lin1b,
    const float* __restrict__ lin2W,
    const float* __restrict__ lin2b,
    float*       __restrict__ out)
{
    __shared__ float gs[LAYERS * D];
    __shared__ float red[LAYERS * D];
    const int g   = blockIdx.x;
    const int tid = threadIdx.x;
    gs[tid] = pool[g * (LAYERS * D) + tid];
    __syncthreads();

    float acc = lin1b[tid];
    #pragma unroll 4
    for (int k = 0; k < LAYERS * D; ++k)
        acc = fmaf(gs[k], lin1W[k * (LAYERS * D) + tid], acc);
    acc = fmaxf(acc, 0.0f);
    float p = acc * lin2W[tid];

    red[tid] = p;
    __syncthreads();
    if (tid < 128) red[tid] = red[tid] + red[tid + 128] + red[tid + 256];
    __syncthreads();
    if (tid < 64) {
        float v = red[tid] + red[tid + 64];
        v += __shfl_down(v, 32);
        v += __shfl_down(v, 16);
        v += __shfl_down(v, 8);
        v += __shfl_down(v, 4);
        v += __shfl_down(v, 2);
        v += __shfl_down(v, 1);
        if (tid == 0) out[g] = v + lin2b[0];
    }
}

// ---------------------------------------------------------------------------
extern "C" void kernel_launch(void* const* d_in, const int* in_sizes, int n_in,
                              void* d_out, int out_size, void* d_ws, size_t ws_size,
                              hipStream_t stream)
{
    const float* x         = (const float*)d_in[0];
    const float* edge_attr = (const float*)d_in[1];
    const float* elW       = (const float*)d_in[2];
    const float* elb       = (const float*)d_in[3];
    const float* W1        = (const float*)d_in[4];
    const float* b1        = (const float*)d_in[5];
    const float* bn_g      = (const float*)d_in[6];
    const float* bn_b      = (const float*)d_in[7];
    const float* bn_mean   = (const float*)d_in[8];
    const float* bn_var    = (const float*)d_in[9];
    const float* W2        = (const float*)d_in[10];
    const float* b2        = (const float*)d_in[11];
    const float* lin1W     = (const float*)d_in[12];
    const float* lin1b     = (const float*)d_in[13];
    const float* lin2W     = (const float*)d_in[14];
    const float* lin2b     = (const float*)d_in[15];
    const int*   ei        = (const int*)d_in[16];
    const int*   batch     = (const int*)d_in[17];
    const int*   src = ei;
    const int*   dst = ei + N_EDGES;

    // Workspace layout, all 16B-aligned:
    float*          pool       = (float*)d_ws;                              // G*384 f32
    unsigned short* xb         = (unsigned short*)(pool + (size_t)N_GRAPHS * LAYERS * D);
    unsigned short* hA_b       = xb   + (size_t)N_NODES * D;                // bf16
    float*          zin_f      = (float*)(hA_b + (size_t)N_NODES * D);      // [N][128] f32
    unsigned short* Wt         = (unsigned short*)(zin_f + (size_t)N_NODES * D);
    uint4*          elWf       = (uint4*)(Wt + 6 * D * D);                  // 3*8*64 uint4
    u32*            sorted_eah = (u32*)(elWf + LAYERS * 8 * 64);            // E*8 u32
    int*            srcdst     = (int*)(sorted_eah + (size_t)N_EDGES * 8);  // E int2
    int*            counts     = srcdst + (size_t)N_EDGES * 2;
    int*            offsets    = counts + N_NODES;                          // N+1
    int*            cursor     = offsets + N_NODES + 4;
    int*            goff       = cursor + N_NODES + 4;                      // 513 ints
    int*            blocksum   = goff + N_GRAPHS + 4;
    int*            blockbase  = blocksum + SCAN_NB + 4;

    hipMemsetAsync(counts, 0, (size_t)N_NODES * sizeof(int), stream);
    hipMemsetAsync(zin_f, 0, (size_t)N_NODES * D * sizeof(float), stream);

    // --- once-per-call prep ---
    wprep_kernel<<<6, 256, 0, stream>>>(W1, W2, Wt);
    elprep_kernel<<<LAYERS, 512, 0, stream>>>(elW, elb, elWf);
    xprep_kernel<<<(N_NODES * D) / 256, 256, 0, stream>>>(x, xb);
    goff_kernel<<<1, 512, 0, stream>>>(batch, goff);
    hist_kernel<<<N_EDGES / 256, 256, 0, stream>>>(dst, counts);
    scan1_kernel<<<SCAN_NB, 256, 0, stream>>>(counts, blocksum);
    scan2_kernel<<<1, 256, 0, stream>>>(blocksum, blockbase);
    scan3_kernel<<<SCAN_NB, 256, 0, stream>>>(counts, blockbase, offsets, cursor);
    scatter_kernel<<<N_EDGES / 256, 256, 0, stream>>>(
        src, dst, edge_attr, cursor, (int2*)srcdst, (uint4*)sorted_eah);

    const unsigned short* hin_b = xb;
    for (int l = 0; l < LAYERS; ++l) {
        aggr_kernel<<<AGGR_BLK, 128, 0, stream>>>(
            hin_b, (const uint4*)sorted_eah, srcdst,
            elWf + (size_t)l * 8 * 64, zin_f);
        node_mlp<<<(N_NODES + 63) / 64, 128, 0, stream>>>(
            zin_f, hin_b,
            Wt + (size_t)(l * 2)     * D * D, b1 + l * D,
            bn_g + l * D, bn_b + l * D, bn_mean + l * D, bn_var + l * D,
            Wt + (size_t)(l * 2 + 1) * D * D, b2 + l * D,
            hA_b, (l < LAYERS - 1) ? 1 : 0);
        pool_kernel<<<N_GRAPHS, 512, 0, stream>>>(hA_b, goff, pool, l * D);
        hin_b = hA_b;
    }

    head_kernel<<<N_GRAPHS, LAYERS * D, 0, stream>>>(
        pool, lin1W, lin1b, lin2W, lin2b, (float*)d_out);
}